// Round 15
// baseline (400.550 us; speedup 1.0000x reference)
//
#include <hip/hip_runtime.h>

typedef unsigned short u16;
typedef unsigned int u32;
typedef __bf16 bf16x8 __attribute__((ext_vector_type(8)));
typedef float f32x4 __attribute__((ext_vector_type(4)));
typedef int i32x4 __attribute__((ext_vector_type(4)));

#define BATCH 8
#define CH 96
#define HWSZ 16384
#define PADP (130*130*96)   // elems per padded plane-image

// ---- workspace layout (bytes) ----
#define OFF_FQ     0ULL          // f32 NHWC (convqk..gprep)
#define OFF_FK     50331648ULL   // f32 NHWC (convqk..pattn); then:
#define OFF_GT     50331648ULL   //   bf16 [B][C][x][y] (gprep..final)
#define OFF_FVN    75497472ULL   //   bf16 [B][C][y][x] (gprep..final)
#define OFF_PAD1H  100663296ULL  // bf16 padded (trans..convqk) 25958400
#define OFF_F1W    100663296ULL  //   bf16 NHWC F1tilde (pattn..fcfr2)
#define OFF_PART   126621696ULL  // f32 [B][128][96][96] 37.75MB (pattn..softmax)
#define OFF_PAD1L  126621696ULL  // bf16 padded (trans..convqk)
#define OFF_PAD2   152580096ULL  // bf16 padded (trans..convv)
#define OFF_FCFR   152580096ULL  //   bf16 [B][C][y][x] (fcfr2..final)
#define OFF_FVB    178538496ULL  // bf16 NHWC (convv..gprep)
#define OFF_ATTNB  203704320ULL  // bf16 [B][96][96]
#define OFF_WQK    203851776ULL  // bf16 packed [27][plane2][g4][co192][8]: 663552B
#define OFF_WV     204515328ULL  // bf16 packed [27][4][96][8]: 165888
#define WS_NEED    204681216ULL

__device__ __forceinline__ u16 f2bf(float f) {
    u32 u = __builtin_bit_cast(u32, f);
    u += 0x7fffu + ((u >> 16) & 1u);
    return (u16)(u >> 16);
}
__device__ __forceinline__ float bf2f(u16 h) {
    u32 u = ((u32)h) << 16;
    return __builtin_bit_cast(float, u);
}
__device__ __forceinline__ f32x4 mfma16(i32x4 a, i32x4 b, f32x4 c) {
    return __builtin_amdgcn_mfma_f32_16x16x32_bf16(
        __builtin_bit_cast(bf16x8, a), __builtin_bit_cast(bf16x8, b), c, 0, 0, 0);
}
__device__ __forceinline__ void gl_lds16(const u16* g, u16* l) {
    __builtin_amdgcn_global_load_lds(
        (const __attribute__((address_space(1))) unsigned int*)g,
        (__attribute__((address_space(3))) unsigned int*)l, 16, 0, 0);
}

__global__ __launch_bounds__(256) void k_diag(float* __restrict__ out, int n, float val) {
    for (int i = blockIdx.x * 256 + threadIdx.x; i < n; i += gridDim.x * 256) out[i] = val;
}

// ---- zero halo of the 3 contiguous padded planes (24 images) ----
__global__ __launch_bounds__(256) void k_zhalo(u16* __restrict__ p) {
    size_t base = (size_t)blockIdx.x * PADP;
    for (int i = threadIdx.x; i < 130 * 96; i += 256) {
        p[base + i] = 0;
        p[base + (size_t)129 * 130 * 96 + i] = 0;
    }
    for (int i = threadIdx.x; i < 128 * 2 * 96; i += 256) {
        int row = i / 192, k = i - row * 192;
        int x = (k < 96) ? 0 : 129, c = (k < 96) ? k : k - 96;
        p[base + ((size_t)(row + 1) * 130 + x) * 96 + c] = 0;
    }
}

// ---- both inputs: NCHW f32 -> padded NHWC bf16 (in1: hi+lo, in2: hi) ----
__global__ __launch_bounds__(256) void k_trans2(const float* __restrict__ in1,
        const float* __restrict__ in2, u16* __restrict__ p1h, u16* __restrict__ p1l,
        u16* __restrict__ p2) {
    __shared__ float tile[96][129];
    int which = blockIdx.x >> 10;
    int blk = blockIdx.x & 1023;
    const float* src = which ? in2 : in1;
    u16* dh = which ? p2 : p1h;
    u16* dl = which ? nullptr : p1l;
    int b = blk >> 7, y = blk & 127;
    const float* s = src + (size_t)b * CH * HWSZ + (size_t)y * 128;
    for (int idx = threadIdx.x; idx < CH * 128; idx += 256) {
        int c = idx >> 7, x = idx & 127;
        tile[c][x] = s[(size_t)c * HWSZ + x];
    }
    __syncthreads();
    size_t obase = ((size_t)(b * 130 + y + 1) * 130 + 1) * 96;
    for (int idx = threadIdx.x; idx < 128 * CH; idx += 256) {
        int x = idx / CH, c = idx - x * CH;
        float v = tile[c][x];
        u16 h = f2bf(v);
        dh[obase + idx] = h;
        if (dl) dl[obase + idx] = f2bf(v - bf2f(h));
    }
}

// ---- weights: QK -> [s=cic*9+tap][plane][g][co192][8] hi/lo; V -> [s][g][96][8] ----
__global__ __launch_bounds__(128) void k_weights_all(const float* __restrict__ wq,
        const float* __restrict__ wk, const float* __restrict__ wv,
        u16* __restrict__ dqk, u16* __restrict__ dv) {
    int co = blockIdx.x;  // 0..287
    if (co < 192) {
        const float* w = (co < 96) ? wq : wk;
        int cs = (co < 96) ? co : co - 96;
        for (int idx = threadIdx.x; idx < 864; idx += 128) {
            int tap = idx / 96, ci = idx - tap * 96;
            int cic = ci >> 5, g = (ci >> 3) & 3, c7 = ci & 7;
            float v = w[((size_t)cs * 96 + ci) * 9 + tap];
            u16 h = f2bf(v), lo = f2bf(v - bf2f(h));
            size_t s = (size_t)(cic * 9 + tap);
            dqk[(((s * 2 + 0) * 4 + g) * 192 + co) * 8 + c7] = h;
            dqk[(((s * 2 + 1) * 4 + g) * 192 + co) * 8 + c7] = lo;
        }
    } else {
        int cs = co - 192;
        for (int idx = threadIdx.x; idx < 864; idx += 128) {
            int tap = idx / 96, ci = idx - tap * 96;
            int cic = ci >> 5, g = (ci >> 3) & 3, c7 = ci & 7;
            float v = wv[((size_t)cs * 96 + ci) * 9 + tap];
            size_t s = (size_t)(cic * 9 + tap);
            dv[((s * 4 + g) * 96 + cs) * 8 + c7] = f2bf(v);
        }
    }
}

// ---- A/B variant 1: EXACT round-9 champion structure, batches 0-3 ----
__global__ __launch_bounds__(512, 4) void k_convqk6h(
        const u16* __restrict__ ph, const u16* __restrict__ pl,
        const u16* __restrict__ wqk,
        const float* __restrict__ bq, const float* __restrict__ bk,
        float* __restrict__ fq, float* __restrict__ fk, int bbase) {
    __shared__ u16 wbuf[2][12288];
    const int tid = threadIdx.x;
    const int wg = ((blockIdx.x & 7) << 6) | (blockIdx.x >> 3);
    const int b = bbase + (wg >> 7), y = wg & 127;
    const int w = tid >> 6, lane = tid & 63, l15 = lane & 15, g = lane >> 4;
    const int wx = w & 3, wc = w >> 2;
    f32x4 acc[2][6];
#pragma unroll
    for (int mf = 0; mf < 2; mf++)
#pragma unroll
        for (int f = 0; f < 6; f++) acc[mf][f] = (f32x4){0.f, 0.f, 0.f, 0.f};
    {
#pragma unroll
        for (int j = 0; j < 3; j++)
            gl_lds16(wqk + (size_t)(tid + j * 512) * 8, &wbuf[0][(size_t)(tid + j * 512) * 8]);
    }
    i32x4 ah0, ah1, al0, al1;
    {
        size_t ab = ((size_t)(b * 130 + y) * 130 + (wx * 32 + l15)) * 96 + g * 8;
        ah0 = *(const i32x4*)(ph + ab);
        ah1 = *(const i32x4*)(ph + ab + 16 * 96);
        al0 = *(const i32x4*)(pl + ab);
        al1 = *(const i32x4*)(pl + ab + 16 * 96);
    }
    __syncthreads();
    for (int s = 0; s < 27; s++) {
        const int cur = s & 1;
        i32x4 nh0, nh1, nl0, nl1;
        if (s + 1 < 27) {
            const u16* src = wqk + (size_t)(s + 1) * 12288;
#pragma unroll
            for (int j = 0; j < 3; j++)
                gl_lds16(src + (size_t)(tid + j * 512) * 8, &wbuf[cur ^ 1][(size_t)(tid + j * 512) * 8]);
            const int s1 = s + 1;
            const int cic1 = s1 / 9, tap1 = s1 - cic1 * 9;
            const int dy1 = tap1 / 3 - 1, dx1 = tap1 - (tap1 / 3) * 3 - 1;
            size_t ab = ((size_t)(b * 130 + y + 1 + dy1) * 130 + (wx * 32 + l15 + 1 + dx1)) * 96
                      + cic1 * 32 + g * 8;
            nh0 = *(const i32x4*)(ph + ab);
            nh1 = *(const i32x4*)(ph + ab + 16 * 96);
            nl0 = *(const i32x4*)(pl + ab);
            nl1 = *(const i32x4*)(pl + ab + 16 * 96);
        }
#pragma unroll
        for (int f = 0; f < 6; f++) {
            const int cob = wc * 96 + f * 16 + l15;
            i32x4 bh = *(const i32x4*)(&wbuf[cur][((0 + g) * 192 + cob) * 8]);
            i32x4 bl = *(const i32x4*)(&wbuf[cur][((4 + g) * 192 + cob) * 8]);
            acc[0][f] = mfma16(ah0, bh, acc[0][f]);
            acc[0][f] = mfma16(ah0, bl, acc[0][f]);
            acc[0][f] = mfma16(al0, bh, acc[0][f]);
            acc[1][f] = mfma16(ah1, bh, acc[1][f]);
            acc[1][f] = mfma16(ah1, bl, acc[1][f]);
            acc[1][f] = mfma16(al1, bh, acc[1][f]);
        }
        __syncthreads();
        if (s + 1 < 27) { ah0 = nh0; ah1 = nh1; al0 = nl0; al1 = nl1; }
    }
    const float* bias = wc ? bk : bq;
    float* op = wc ? fk : fq;
#pragma unroll
    for (int f = 0; f < 6; f++) {
        const int co = f * 16 + l15;
        const float bb = bias[co];
#pragma unroll
        for (int mf = 0; mf < 2; mf++) {
            const int xp = wx * 32 + mf * 16 + g * 4;
#pragma unroll
            for (int r = 0; r < 4; r++)
                op[((size_t)((b * 128 + y) * 128 + xp + r)) * 96 + co] = acc[mf][f][r] + bb;
        }
    }
}

// ---- A/B variant 2: NO LDS, NO BARRIERS — B direct from global (L1/L2-hot), b4-7 ----
__global__ __launch_bounds__(512, 4) void k_convqk9(
        const u16* __restrict__ ph, const u16* __restrict__ pl,
        const u16* __restrict__ wqk,
        const float* __restrict__ bq, const float* __restrict__ bk,
        float* __restrict__ fq, float* __restrict__ fk, int bbase) {
    const int tid = threadIdx.x;
    const int wg = ((blockIdx.x & 7) << 6) | (blockIdx.x >> 3);
    const int b = bbase + (wg >> 7), y = wg & 127;
    const int w = tid >> 6, lane = tid & 63, l15 = lane & 15, g = lane >> 4;
    const int wx = w & 3, wc = w >> 2;
    f32x4 acc[2][6];
#pragma unroll
    for (int mf = 0; mf < 2; mf++)
#pragma unroll
        for (int f = 0; f < 6; f++) acc[mf][f] = (f32x4){0.f, 0.f, 0.f, 0.f};
    i32x4 ah0, ah1, al0, al1;
    {
        size_t ab = ((size_t)(b * 130 + y) * 130 + (wx * 32 + l15)) * 96 + g * 8;
        ah0 = *(const i32x4*)(ph + ab);
        ah1 = *(const i32x4*)(ph + ab + 16 * 96);
        al0 = *(const i32x4*)(pl + ab);
        al1 = *(const i32x4*)(pl + ab + 16 * 96);
    }
    for (int s = 0; s < 27; s++) {
        i32x4 nh0, nh1, nl0, nl1;
        if (s + 1 < 27) {   // prefetch next A only
            const int s1 = s + 1;
            const int cic1 = s1 / 9, tap1 = s1 - cic1 * 9;
            const int dy1 = tap1 / 3 - 1, dx1 = tap1 - (tap1 / 3) * 3 - 1;
            size_t ab = ((size_t)(b * 130 + y + 1 + dy1) * 130 + (wx * 32 + l15 + 1 + dx1)) * 96
                      + cic1 * 32 + g * 8;
            nh0 = *(const i32x4*)(ph + ab);
            nh1 = *(const i32x4*)(ph + ab + 16 * 96);
            nl0 = *(const i32x4*)(pl + ab);
            nl1 = *(const i32x4*)(pl + ab + 16 * 96);
        }
        const u16* wstep = wqk + (size_t)s * 12288;
#pragma unroll
        for (int f = 0; f < 6; f++) {
            const int cob = wc * 96 + f * 16 + l15;
            i32x4 bh = *(const i32x4*)(wstep + (size_t)((0 + g) * 192 + cob) * 8);
            i32x4 bl = *(const i32x4*)(wstep + (size_t)((4 + g) * 192 + cob) * 8);
            acc[0][f] = mfma16(ah0, bh, acc[0][f]);
            acc[0][f] = mfma16(ah0, bl, acc[0][f]);
            acc[0][f] = mfma16(al0, bh, acc[0][f]);
            acc[1][f] = mfma16(ah1, bh, acc[1][f]);
            acc[1][f] = mfma16(ah1, bl, acc[1][f]);
            acc[1][f] = mfma16(al1, bh, acc[1][f]);
        }
        if (s + 1 < 27) { ah0 = nh0; ah1 = nh1; al0 = nl0; al1 = nl1; }
    }
    const float* bias = wc ? bk : bq;
    float* op = wc ? fk : fq;
#pragma unroll
    for (int f = 0; f < 6; f++) {
        const int co = f * 16 + l15;
        const float bb = bias[co];
#pragma unroll
        for (int mf = 0; mf < 2; mf++) {
            const int xp = wx * 32 + mf * 16 + g * 4;
#pragma unroll
            for (int r = 0; r < 4; r++)
                op[((size_t)((b * 128 + y) * 128 + xp + r)) * 96 + co] = acc[mf][f][r] + bb;
        }
    }
}

// ---- V conv: round-9 structure ----
__global__ __launch_bounds__(512, 4) void k_convv6(
        const u16* __restrict__ p2, const u16* __restrict__ wv,
        const float* __restrict__ bv, u16* __restrict__ fvb) {
    __shared__ u16 vbuf[2][3072];
    const int tid = threadIdx.x;
    const int wg = ((blockIdx.x & 7) << 7) | (blockIdx.x >> 3);
    const int b = wg >> 7, y = wg & 127;
    const int w = tid >> 6, lane = tid & 63, l15 = lane & 15, g = lane >> 4;
    const int wx = w & 3, wc = w >> 2;
    f32x4 acc[2][3];
#pragma unroll
    for (int mf = 0; mf < 2; mf++)
#pragma unroll
        for (int f = 0; f < 3; f++) acc[mf][f] = (f32x4){0.f, 0.f, 0.f, 0.f};
    if (tid < 384)
        gl_lds16(wv + (size_t)tid * 8, &vbuf[0][(size_t)tid * 8]);
    i32x4 ah0, ah1;
    {
        size_t ab = ((size_t)(b * 130 + y) * 130 + (wx * 32 + l15)) * 96 + g * 8;
        ah0 = *(const i32x4*)(p2 + ab);
        ah1 = *(const i32x4*)(p2 + ab + 16 * 96);
    }
    __syncthreads();
    for (int s = 0; s < 27; s++) {
        const int cur = s & 1;
        i32x4 nh0, nh1;
        if (s + 1 < 27) {
            if (tid < 384)
                gl_lds16(wv + (size_t)(s + 1) * 3072 + (size_t)tid * 8, &vbuf[cur ^ 1][(size_t)tid * 8]);
            const int s1 = s + 1;
            const int cic1 = s1 / 9, tap1 = s1 - cic1 * 9;
            const int dy1 = tap1 / 3 - 1, dx1 = tap1 - (tap1 / 3) * 3 - 1;
            size_t ab = ((size_t)(b * 130 + y + 1 + dy1) * 130 + (wx * 32 + l15 + 1 + dx1)) * 96
                      + cic1 * 32 + g * 8;
            nh0 = *(const i32x4*)(p2 + ab);
            nh1 = *(const i32x4*)(p2 + ab + 16 * 96);
        }
#pragma unroll
        for (int f = 0; f < 3; f++) {
            const int cof = wc * 48 + f * 16 + l15;
            i32x4 bfr = *(const i32x4*)(&vbuf[cur][(g * 96 + cof) * 8]);
            acc[0][f] = mfma16(ah0, bfr, acc[0][f]);
            acc[1][f] = mfma16(ah1, bfr, acc[1][f]);
        }
        __syncthreads();
        if (s + 1 < 27) { ah0 = nh0; ah1 = nh1; }
    }
#pragma unroll
    for (int f = 0; f < 3; f++) {
        const int co = wc * 48 + f * 16 + l15;
        const float bb = bv[co];
#pragma unroll
        for (int mf = 0; mf < 2; mf++) {
            const int xp = wx * 32 + mf * 16 + g * 4;
#pragma unroll
            for (int r = 0; r < 4; r++)
                fvb[((size_t)((b * 128 + y) * 128 + xp + r)) * 96 + co] = f2bf(acc[mf][f][r] + bb);
        }
    }
}

// ---- FUSED patch+attn (round-10 proven shape): 1024 blocks, 2x 64-px chunks ----
__global__ __launch_bounds__(256) void k_pattn2(
        const float* __restrict__ fq, const float* __restrict__ fk,
        u16* __restrict__ f1w, float* __restrict__ part) {
    __shared__ float qs[96 * 65];
    __shared__ float ks[96 * 65];
    int wg = ((blockIdx.x & 7) << 7) | (blockIdx.x >> 3);   // XCD swizzle
    int b = wg >> 7, ys = (wg >> 2) & 31, xq = wg & 3;
    int y0 = ys * 4, x0 = xq * 32;
    int tx = threadIdx.x & 15, ty = threadIdx.x >> 4;
    double accD[6][6];
#pragma unroll
    for (int a = 0; a < 6; a++)
#pragma unroll
        for (int bb = 0; bb < 6; bb++) accD[a][bb] = 0.0;
#pragma unroll
    for (int cx = 0; cx < 2; cx++) {
        for (int idx = threadIdx.x; idx < 1536; idx += 256) {
            int p = idx / 24, c0 = (idx - p * 24) * 4;
            int ry = p >> 4, rx = p & 15;
            size_t off = ((size_t)((b * 128 + y0 + ry) * 128 + x0 + cx * 16 + rx)) * 96 + c0;
            f32x4 qv = *(const f32x4*)(fq + off);
            f32x4 kv = *(const f32x4*)(fk + off);
#pragma unroll
            for (int u = 0; u < 4; u++) {
                qs[(c0 + u) * 65 + p] = qv[u];
                ks[(c0 + u) * 65 + p] = kv[u];
            }
        }
        __syncthreads();
        for (int item = threadIdx.x; item < 384; item += 256) {
            int j = item / 96, c = item - j * 96;
            float A[4][4], Bm[4][4];
#pragma unroll
            for (int r = 0; r < 4; r++)
#pragma unroll
                for (int m = 0; m < 4; m++) {
                    A[r][m] = qs[c * 65 + r * 16 + j * 4 + m];
                    Bm[r][m] = ks[c * 65 + r * 16 + j * 4 + m];
                }
            float rsB[4], csB[4], rsA[4], tot = 0.f;
#pragma unroll
            for (int r = 0; r < 4; r++) {
                rsB[r] = Bm[r][0] + Bm[r][1] + Bm[r][2] + Bm[r][3];
                rsA[r] = A[r][0] + A[r][1] + A[r][2] + A[r][3];
                tot += rsB[r];
            }
#pragma unroll
            for (int m = 0; m < 4; m++) csB[m] = Bm[0][m] + Bm[1][m] + Bm[2][m] + Bm[3][m];
#pragma unroll
            for (int r = 0; r < 4; r++)
#pragma unroll
                for (int m = 0; m < 4; m++) {
                    float ab = A[r][0] * Bm[0][m] + A[r][1] * Bm[1][m]
                             + A[r][2] * Bm[2][m] + A[r][3] * Bm[3][m];
                    f1w[((size_t)((b * 128 + y0 + r) * 128 + x0 + cx * 16 + j * 4 + m)) * 96 + c]
                        = f2bf(8.f * ab + 2.f * rsA[r] * csB[m]);
                }
#pragma unroll
            for (int r = 0; r < 4; r++)
#pragma unroll
                for (int m = 0; m < 4; m++)
                    ks[c * 65 + r * 16 + j * 4 + m]
                        = 64.f * Bm[r][m] + 16.f * (rsB[r] + csB[m]) + 4.f * tot;
        }
        __syncthreads();
        float acc[6][6];
#pragma unroll
        for (int a = 0; a < 6; a++)
#pragma unroll
            for (int bb = 0; bb < 6; bb++) acc[a][bb] = 0.f;
        for (int l = 0; l < 64; l++) {
            float qv[6], kv[6];
#pragma unroll
            for (int a = 0; a < 6; a++) qv[a] = qs[(ty + 16 * a) * 65 + l];
#pragma unroll
            for (int bb = 0; bb < 6; bb++) kv[bb] = ks[(tx + 16 * bb) * 65 + l];
#pragma unroll
            for (int a = 0; a < 6; a++)
#pragma unroll
                for (int bb = 0; bb < 6; bb++) acc[a][bb] += qv[a] * kv[bb];
        }
#pragma unroll
        for (int a = 0; a < 6; a++)
#pragma unroll
            for (int bb = 0; bb < 6; bb++) accD[a][bb] += (double)acc[a][bb];
        __syncthreads();
    }
    int s128 = ys * 4 + xq;
#pragma unroll
    for (int a = 0; a < 6; a++)
#pragma unroll
        for (int bb = 0; bb < 6; bb++)
            part[((size_t)((b * 128 + s128) * 96 + ty + 16 * a)) * 96 + tx + 16 * bb]
                = (float)accD[a][bb];
}

// ---- reduce 128 slices (f64) + temperature + row softmax -> bf16 weights ----
__global__ __launch_bounds__(128) void k_softmax(
        const float* __restrict__ part, const float* __restrict__ temp,
        u16* __restrict__ attnb) {
    __shared__ float red[128];
    int b = blockIdx.x / 96, i2 = blockIdx.x - b * 96;
    int j2 = threadIdx.x;
    float v = 0.f;
    if (j2 < 96) {
        double vd = 0.0;
        for (int s = 0; s < 128; s++)
            vd += (double)part[((size_t)((b * 128 + s) * 96 + i2)) * 96 + j2];
        v = (float)vd * temp[0];
    }
    red[j2] = (j2 < 96) ? v : -3.4e38f;
    __syncthreads();
    for (int off = 64; off >= 1; off >>= 1) {
        if (j2 < off) red[j2] = fmaxf(red[j2], red[j2 + off]);
        __syncthreads();
    }
    float mx = red[0];
    __syncthreads();
    float e = (j2 < 96) ? expf(v - mx) : 0.f;
    red[j2] = e;
    __syncthreads();
    for (int off = 64; off >= 1; off >>= 1) {
        if (j2 < off) red[j2] += red[j2 + off];
        __syncthreads();
    }
    float sum = red[0];
    if (j2 < 96) attnb[((size_t)(b * 96) + i2) * 96 + j2] = f2bf(e / sum);
}

// ---- Gt = (F_Q - 0.5 F_V)^T, Fvn = F_V, both bf16 [B][C][.][.] ----
__global__ __launch_bounds__(256) void k_gprep(
        const float* __restrict__ fqn, const u16* __restrict__ fvb,
        u16* __restrict__ gt, u16* __restrict__ fvn) {
    __shared__ u16 lg[8 * 32 * 33];
    __shared__ u16 lv[8 * 32 * 33];
    int blk = blockIdx.x;
    int b = blk / 192;
    int r = blk - b * 192;
    int yt = r / 48; r -= yt * 48;
    int xt = r / 12; int cc = r - xt * 12;
    int y0 = yt * 32, x0 = xt * 32, c0 = cc * 8;
    for (int idx = threadIdx.x; idx < 8192; idx += 256) {
        int pix = idx >> 3, cl = idx & 7;
        int yy = pix >> 5, xx = pix & 31;
        size_t off = ((size_t)((b * 128 + y0 + yy) * 128 + x0 + xx)) * 96 + c0 + cl;
        float q = fqn[off];
        float v = bf2f(fvb[off]);
        int la = (cl * 32 + yy) * 33 + xx;
        lg[la] = f2bf(q - 0.5f * v);
        lv[la] = f2bf(v);
    }
    __syncthreads();
    for (int idx = threadIdx.x; idx < 8192; idx += 256) {
        int yy = idx & 31, xl = (idx >> 5) & 31, cl = idx >> 10;
        gt[((size_t)((b * 96 + c0 + cl) * 128 + x0 + xl)) * 128 + y0 + yy] = lg[(cl * 32 + yy) * 33 + xl];
    }
    for (int idx = threadIdx.x; idx < 8192; idx += 256) {
        int xx = idx & 31, yl = (idx >> 5) & 31, cl = idx >> 10;
        fvn[((size_t)((b * 96 + c0 + cl) * 128 + y0 + yl)) * 128 + x0 + xx] = lv[(cl * 32 + yl) * 33 + xx];
    }
}

// ---- FCFR[b][i][pix] = sum_j attn[i][j] * F1W[b][pix][j]  (bf16 MFMA) ----
__global__ __launch_bounds__(256) void k_fcfr2(
        const u16* __restrict__ attnb, const u16* __restrict__ f1w,
        u16* __restrict__ fc) {
    int b = blockIdx.x >> 6, pc = blockIdx.x & 63;
    int lane = threadIdx.x & 63, wv_ = threadIdx.x >> 6;
    int l15 = lane & 15, g = lane >> 4;
    int pbase = pc * 256 + wv_ * 64;
    f32x4 acc[6][4];
#pragma unroll
    for (int m = 0; m < 6; m++)
#pragma unroll
        for (int n = 0; n < 4; n++) acc[m][n] = (f32x4){0.f, 0.f, 0.f, 0.f};
#pragma unroll
    for (int ks = 0; ks < 3; ks++) {
        int k0 = ks * 32 + g * 8;
        i32x4 afr[6];
#pragma unroll
        for (int m = 0; m < 6; m++)
            afr[m] = *(const i32x4*)(attnb + ((size_t)(b * 96 + m * 16 + l15)) * 96 + k0);
#pragma unroll
        for (int n = 0; n < 4; n++) {
            i32x4 bfr = *(const i32x4*)(f1w + ((size_t)(b * 16384 + pbase + n * 16 + l15)) * 96 + k0);
#pragma unroll
            for (int m = 0; m < 6; m++)
                acc[m][n] = mfma16(afr[m], bfr, acc[m][n]);
        }
    }
#pragma unroll
    for (int m = 0; m < 6; m++)
#pragma unroll
        for (int n = 0; n < 4; n++)
#pragma unroll
            for (int r = 0; r < 4; r++) {
                int i2 = m * 16 + g * 4 + r;
                int pix = pbase + n * 16 + l15;
                fc[((size_t)(b * 96 + i2)) * HWSZ + pix] = f2bf(acc[m][n][r]);
            }
}

// ---- out = Fcfrout @ (F_Q - 0.5 F_V) + F_V  (bf16 MFMA, per (b,c) 128^3) ----
__global__ __launch_bounds__(256) void k_final(
        const u16* __restrict__ fc, const u16* __restrict__ gt,
        const u16* __restrict__ fvn, float* __restrict__ out) {
    int b = blockIdx.x / 96, c = blockIdx.x - b * 96;
    int lane = threadIdx.x & 63, wv_ = threadIdx.x >> 6;
    int l15 = lane & 15, g = lane >> 4;
    const u16* A = fc + ((size_t)(b * 96 + c)) * HWSZ;
    const u16* Bm = gt + ((size_t)(b * 96 + c)) * HWSZ;
    f32x4 acc[2][8];
#pragma unroll
    for (int mf = 0; mf < 2; mf++)
#pragma unroll
        for (int nf = 0; nf < 8; nf++) acc[mf][nf] = (f32x4){0.f, 0.f, 0.f, 0.f};
#pragma unroll
    for (int kc = 0; kc < 4; kc++) {
        int k0 = kc * 32 + g * 8;
        i32x4 af[2];
#pragma unroll
        for (int mf = 0; mf < 2; mf++)
            af[mf] = *(const i32x4*)(A + (size_t)(wv_ * 32 + mf * 16 + l15) * 128 + k0);
#pragma unroll
        for (int nf = 0; nf < 8; nf++) {
            i32x4 bf = *(const i32x4*)(Bm + (size_t)(nf * 16 + l15) * 128 + k0);
#pragma unroll
            for (int mf = 0; mf < 2; mf++)
                acc[mf][nf] = mfma16(af[mf], bf, acc[mf][nf]);
        }
    }
    const u16* V = fvn + ((size_t)(b * 96 + c)) * HWSZ;
    float* O = out + ((size_t)(b * 96 + c)) * HWSZ;
#pragma unroll
    for (int mf = 0; mf < 2; mf++)
#pragma unroll
        for (int nf = 0; nf < 8; nf++)
#pragma unroll
            for (int r = 0; r < 4; r++) {
                int y = wv_ * 32 + mf * 16 + g * 4 + r;
                int x = nf * 16 + l15;
                O[y * 128 + x] = acc[mf][nf][r] + bf2f(V[y * 128 + x]);
            }
}

extern "C" void kernel_launch(void* const* d_in, const int* in_sizes, int n_in,
                              void* d_out, int out_size, void* d_ws, size_t ws_size,
                              hipStream_t stream) {
    (void)in_sizes; (void)n_in;
    if (ws_size < (size_t)WS_NEED) {
        k_diag<<<2048, 256, 0, stream>>>((float*)d_out, out_size, (float)(ws_size >> 10));
        return;
    }
    const float* in1 = (const float*)d_in[0];
    const float* in2 = (const float*)d_in[1];
    const float* wq  = (const float*)d_in[2];
    const float* bq  = (const float*)d_in[3];
    const float* wk  = (const float*)d_in[4];
    const float* bk  = (const float*)d_in[5];
    const float* wv  = (const float*)d_in[6];
    const float* bv  = (const float*)d_in[7];
    const float* temp = (const float*)d_in[8];
    char* ws = (char*)d_ws;
    float* FQ   = (float*)(ws + OFF_FQ);
    float* FK   = (float*)(ws + OFF_FK);
    u16*  GT    = (u16*)(ws + OFF_GT);
    u16*  FVN   = (u16*)(ws + OFF_FVN);
    u16*  PAD1H = (u16*)(ws + OFF_PAD1H);
    u16*  PAD1L = (u16*)(ws + OFF_PAD1L);
    u16*  PAD2  = (u16*)(ws + OFF_PAD2);
    u16*  F1W   = (u16*)(ws + OFF_F1W);
    float* PART = (float*)(ws + OFF_PART);
    u16*  FCFR  = (u16*)(ws + OFF_FCFR);
    u16*  FVB   = (u16*)(ws + OFF_FVB);
    u16*  ATTNB = (u16*)(ws + OFF_ATTNB);
    u16*  WQK   = (u16*)(ws + OFF_WQK);
    u16*  WV    = (u16*)(ws + OFF_WV);

    k_zhalo<<<24, 256, 0, stream>>>(PAD1H);
    k_trans2<<<2048, 256, 0, stream>>>(in1, in2, PAD1H, PAD1L, PAD2);
    k_weights_all<<<288, 128, 0, stream>>>(wq, wk, wv, WQK, WV);
    // A/B: LDS-staged champion (batches 0-3) vs no-LDS no-barrier global-B (batches 4-7)
    k_convqk6h<<<512, 512, 0, stream>>>(PAD1H, PAD1L, WQK, bq, bk, FQ, FK, 0);
    k_convqk9<<<512, 512, 0, stream>>>(PAD1H, PAD1L, WQK, bq, bk, FQ, FK, 4);
    k_convv6<<<1024, 512, 0, stream>>>(PAD2, WV, bv, FVB);
    k_pattn2<<<1024, 256, 0, stream>>>(FQ, FK, F1W, PART);
    k_softmax<<<768, 128, 0, stream>>>(PART, temp, ATTNB);
    k_gprep<<<1536, 256, 0, stream>>>(FQ, FVB, GT, FVN);
    k_fcfr2<<<512, 256, 0, stream>>>(ATTNB, F1W, FCFR);
    k_final<<<768, 256, 0, stream>>>(FCFR, GT, FVN, (float*)d_out);
}

// Round 16
// 379.009 us; speedup vs baseline: 1.0568x; 1.0568x over previous
//
#include <hip/hip_runtime.h>

typedef unsigned short u16;
typedef unsigned int u32;
typedef __bf16 bf16x8 __attribute__((ext_vector_type(8)));
typedef float f32x4 __attribute__((ext_vector_type(4)));
typedef int i32x4 __attribute__((ext_vector_type(4)));

#define BATCH 8
#define CH 96
#define HWSZ 16384
#define PADP (130*130*96)   // elems per padded plane-image

// ---- workspace layout (bytes) ----
#define OFF_FQ     0ULL          // f32 NHWC (convqk..gprep)
#define OFF_FK     50331648ULL   // f32 NHWC (convqk..pattn); then:
#define OFF_GT     50331648ULL   //   bf16 [B][C][x][y] (gprep..final)
#define OFF_FVN    75497472ULL   //   bf16 [B][C][y][x] (gprep..final)
#define OFF_PAD1H  100663296ULL  // bf16 padded (trans..convqk) 25958400
#define OFF_F1W    100663296ULL  //   bf16 NHWC F1tilde (pattn..fcfr2)
#define OFF_PART   126621696ULL  // f32 [B][128][96][96] 37.75MB (pattn..softmax)
#define OFF_PAD1L  126621696ULL  // bf16 padded (trans..convqk)
#define OFF_PAD2   152580096ULL  // bf16 padded (trans..convv)
#define OFF_FCFR   152580096ULL  //   bf16 [B][C][y][x] (fcfr2..final)
#define OFF_FVB    178538496ULL  // bf16 NHWC (convv..gprep)
#define OFF_ATTNB  203704320ULL  // bf16 [B][96][96]
#define OFF_WQK    203851776ULL  // bf16 packed [27][plane2][g4][co192][8]: 663552B
#define OFF_WV     204515328ULL  // bf16 packed [27][4][96][8]: 165888
#define WS_NEED    204681216ULL

__device__ __forceinline__ u16 f2bf(float f) {
    u32 u = __builtin_bit_cast(u32, f);
    u += 0x7fffu + ((u >> 16) & 1u);
    return (u16)(u >> 16);
}
__device__ __forceinline__ float bf2f(u16 h) {
    u32 u = ((u32)h) << 16;
    return __builtin_bit_cast(float, u);
}
__device__ __forceinline__ f32x4 mfma16(i32x4 a, i32x4 b, f32x4 c) {
    return __builtin_amdgcn_mfma_f32_16x16x32_bf16(
        __builtin_bit_cast(bf16x8, a), __builtin_bit_cast(bf16x8, b), c, 0, 0, 0);
}
__device__ __forceinline__ void gl_lds16(const u16* g, u16* l) {
    __builtin_amdgcn_global_load_lds(
        (const __attribute__((address_space(1))) unsigned int*)g,
        (__attribute__((address_space(3))) unsigned int*)l, 16, 0, 0);
}

__global__ __launch_bounds__(256) void k_diag(float* __restrict__ out, int n, float val) {
    for (int i = blockIdx.x * 256 + threadIdx.x; i < n; i += gridDim.x * 256) out[i] = val;
}

// ---- zero halo of the 3 contiguous padded planes (24 images) ----
__global__ __launch_bounds__(256) void k_zhalo(u16* __restrict__ p) {
    size_t base = (size_t)blockIdx.x * PADP;
    for (int i = threadIdx.x; i < 130 * 96; i += 256) {
        p[base + i] = 0;
        p[base + (size_t)129 * 130 * 96 + i] = 0;
    }
    for (int i = threadIdx.x; i < 128 * 2 * 96; i += 256) {
        int row = i / 192, k = i - row * 192;
        int x = (k < 96) ? 0 : 129, c = (k < 96) ? k : k - 96;
        p[base + ((size_t)(row + 1) * 130 + x) * 96 + c] = 0;
    }
}

// ---- both inputs: NCHW f32 -> padded NHWC bf16 (in1: hi+lo, in2: hi) ----
__global__ __launch_bounds__(256) void k_trans2(const float* __restrict__ in1,
        const float* __restrict__ in2, u16* __restrict__ p1h, u16* __restrict__ p1l,
        u16* __restrict__ p2) {
    __shared__ float tile[96][129];
    int which = blockIdx.x >> 10;
    int blk = blockIdx.x & 1023;
    const float* src = which ? in2 : in1;
    u16* dh = which ? p2 : p1h;
    u16* dl = which ? nullptr : p1l;
    int b = blk >> 7, y = blk & 127;
    const float* s = src + (size_t)b * CH * HWSZ + (size_t)y * 128;
    for (int idx = threadIdx.x; idx < CH * 128; idx += 256) {
        int c = idx >> 7, x = idx & 127;
        tile[c][x] = s[(size_t)c * HWSZ + x];
    }
    __syncthreads();
    size_t obase = ((size_t)(b * 130 + y + 1) * 130 + 1) * 96;
    for (int idx = threadIdx.x; idx < 128 * CH; idx += 256) {
        int x = idx / CH, c = idx - x * CH;
        float v = tile[c][x];
        u16 h = f2bf(v);
        dh[obase + idx] = h;
        if (dl) dl[obase + idx] = f2bf(v - bf2f(h));
    }
}

// ---- weights: QK -> [s=cic*9+tap][plane][g][co192][8] hi/lo; V -> [s][g][96][8] ----
__global__ __launch_bounds__(128) void k_weights_all(const float* __restrict__ wq,
        const float* __restrict__ wk, const float* __restrict__ wv,
        u16* __restrict__ dqk, u16* __restrict__ dv) {
    int co = blockIdx.x;  // 0..287
    if (co < 192) {
        const float* w = (co < 96) ? wq : wk;
        int cs = (co < 96) ? co : co - 96;
        for (int idx = threadIdx.x; idx < 864; idx += 128) {
            int tap = idx / 96, ci = idx - tap * 96;
            int cic = ci >> 5, g = (ci >> 3) & 3, c7 = ci & 7;
            float v = w[((size_t)cs * 96 + ci) * 9 + tap];
            u16 h = f2bf(v), lo = f2bf(v - bf2f(h));
            size_t s = (size_t)(cic * 9 + tap);
            dqk[(((s * 2 + 0) * 4 + g) * 192 + co) * 8 + c7] = h;
            dqk[(((s * 2 + 1) * 4 + g) * 192 + co) * 8 + c7] = lo;
        }
    } else {
        int cs = co - 192;
        for (int idx = threadIdx.x; idx < 864; idx += 128) {
            int tap = idx / 96, ci = idx - tap * 96;
            int cic = ci >> 5, g = (ci >> 3) & 3, c7 = ci & 7;
            float v = wv[((size_t)cs * 96 + ci) * 9 + tap];
            size_t s = (size_t)(cic * 9 + tap);
            dv[((s * 4 + g) * 96 + cs) * 8 + c7] = f2bf(v);
        }
    }
}

// ---- fused Q+K conv: round-9 champion, single full-grid launch ----
__global__ __launch_bounds__(512, 4) void k_convqk6(
        const u16* __restrict__ ph, const u16* __restrict__ pl,
        const u16* __restrict__ wqk,
        const float* __restrict__ bq, const float* __restrict__ bk,
        float* __restrict__ fq, float* __restrict__ fk) {
    __shared__ u16 wbuf[2][12288];
    const int tid = threadIdx.x;
    const int wg = ((blockIdx.x & 7) << 7) | (blockIdx.x >> 3);  // XCD swizzle: 1 image/XCD
    const int b = wg >> 7, y = wg & 127;
    const int w = tid >> 6, lane = tid & 63, l15 = lane & 15, g = lane >> 4;
    const int wx = w & 3, wc = w >> 2;
    f32x4 acc[2][6];
#pragma unroll
    for (int mf = 0; mf < 2; mf++)
#pragma unroll
        for (int f = 0; f < 6; f++) acc[mf][f] = (f32x4){0.f, 0.f, 0.f, 0.f};
    {
#pragma unroll
        for (int j = 0; j < 3; j++)
            gl_lds16(wqk + (size_t)(tid + j * 512) * 8, &wbuf[0][(size_t)(tid + j * 512) * 8]);
    }
    i32x4 ah0, ah1, al0, al1;
    {
        size_t ab = ((size_t)(b * 130 + y) * 130 + (wx * 32 + l15)) * 96 + g * 8;
        ah0 = *(const i32x4*)(ph + ab);
        ah1 = *(const i32x4*)(ph + ab + 16 * 96);
        al0 = *(const i32x4*)(pl + ab);
        al1 = *(const i32x4*)(pl + ab + 16 * 96);
    }
    __syncthreads();
    for (int s = 0; s < 27; s++) {
        const int cur = s & 1;
        i32x4 nh0, nh1, nl0, nl1;
        if (s + 1 < 27) {
            const u16* src = wqk + (size_t)(s + 1) * 12288;
#pragma unroll
            for (int j = 0; j < 3; j++)
                gl_lds16(src + (size_t)(tid + j * 512) * 8, &wbuf[cur ^ 1][(size_t)(tid + j * 512) * 8]);
            const int s1 = s + 1;
            const int cic1 = s1 / 9, tap1 = s1 - cic1 * 9;
            const int dy1 = tap1 / 3 - 1, dx1 = tap1 - (tap1 / 3) * 3 - 1;
            size_t ab = ((size_t)(b * 130 + y + 1 + dy1) * 130 + (wx * 32 + l15 + 1 + dx1)) * 96
                      + cic1 * 32 + g * 8;
            nh0 = *(const i32x4*)(ph + ab);
            nh1 = *(const i32x4*)(ph + ab + 16 * 96);
            nl0 = *(const i32x4*)(pl + ab);
            nl1 = *(const i32x4*)(pl + ab + 16 * 96);
        }
#pragma unroll
        for (int f = 0; f < 6; f++) {
            const int cob = wc * 96 + f * 16 + l15;
            i32x4 bh = *(const i32x4*)(&wbuf[cur][((0 + g) * 192 + cob) * 8]);
            i32x4 bl = *(const i32x4*)(&wbuf[cur][((4 + g) * 192 + cob) * 8]);
            acc[0][f] = mfma16(ah0, bh, acc[0][f]);
            acc[0][f] = mfma16(ah0, bl, acc[0][f]);
            acc[0][f] = mfma16(al0, bh, acc[0][f]);
            acc[1][f] = mfma16(ah1, bh, acc[1][f]);
            acc[1][f] = mfma16(ah1, bl, acc[1][f]);
            acc[1][f] = mfma16(al1, bh, acc[1][f]);
        }
        __syncthreads();
        if (s + 1 < 27) { ah0 = nh0; ah1 = nh1; al0 = nl0; al1 = nl1; }
    }
    const float* bias = wc ? bk : bq;
    float* op = wc ? fk : fq;
#pragma unroll
    for (int f = 0; f < 6; f++) {
        const int co = f * 16 + l15;
        const float bb = bias[co];
#pragma unroll
        for (int mf = 0; mf < 2; mf++) {
            const int xp = wx * 32 + mf * 16 + g * 4;
#pragma unroll
            for (int r = 0; r < 4; r++)
                op[((size_t)((b * 128 + y) * 128 + xp + r)) * 96 + co] = acc[mf][f][r] + bb;
        }
    }
}

// ---- V conv: round-9 structure ----
__global__ __launch_bounds__(512, 4) void k_convv6(
        const u16* __restrict__ p2, const u16* __restrict__ wv,
        const float* __restrict__ bv, u16* __restrict__ fvb) {
    __shared__ u16 vbuf[2][3072];
    const int tid = threadIdx.x;
    const int wg = ((blockIdx.x & 7) << 7) | (blockIdx.x >> 3);
    const int b = wg >> 7, y = wg & 127;
    const int w = tid >> 6, lane = tid & 63, l15 = lane & 15, g = lane >> 4;
    const int wx = w & 3, wc = w >> 2;
    f32x4 acc[2][3];
#pragma unroll
    for (int mf = 0; mf < 2; mf++)
#pragma unroll
        for (int f = 0; f < 3; f++) acc[mf][f] = (f32x4){0.f, 0.f, 0.f, 0.f};
    if (tid < 384)
        gl_lds16(wv + (size_t)tid * 8, &vbuf[0][(size_t)tid * 8]);
    i32x4 ah0, ah1;
    {
        size_t ab = ((size_t)(b * 130 + y) * 130 + (wx * 32 + l15)) * 96 + g * 8;
        ah0 = *(const i32x4*)(p2 + ab);
        ah1 = *(const i32x4*)(p2 + ab + 16 * 96);
    }
    __syncthreads();
    for (int s = 0; s < 27; s++) {
        const int cur = s & 1;
        i32x4 nh0, nh1;
        if (s + 1 < 27) {
            if (tid < 384)
                gl_lds16(wv + (size_t)(s + 1) * 3072 + (size_t)tid * 8, &vbuf[cur ^ 1][(size_t)tid * 8]);
            const int s1 = s + 1;
            const int cic1 = s1 / 9, tap1 = s1 - cic1 * 9;
            const int dy1 = tap1 / 3 - 1, dx1 = tap1 - (tap1 / 3) * 3 - 1;
            size_t ab = ((size_t)(b * 130 + y + 1 + dy1) * 130 + (wx * 32 + l15 + 1 + dx1)) * 96
                      + cic1 * 32 + g * 8;
            nh0 = *(const i32x4*)(p2 + ab);
            nh1 = *(const i32x4*)(p2 + ab + 16 * 96);
        }
#pragma unroll
        for (int f = 0; f < 3; f++) {
            const int cof = wc * 48 + f * 16 + l15;
            i32x4 bfr = *(const i32x4*)(&vbuf[cur][(g * 96 + cof) * 8]);
            acc[0][f] = mfma16(ah0, bfr, acc[0][f]);
            acc[1][f] = mfma16(ah1, bfr, acc[1][f]);
        }
        __syncthreads();
        if (s + 1 < 27) { ah0 = nh0; ah1 = nh1; }
    }
#pragma unroll
    for (int f = 0; f < 3; f++) {
        const int co = wc * 48 + f * 16 + l15;
        const float bb = bv[co];
#pragma unroll
        for (int mf = 0; mf < 2; mf++) {
            const int xp = wx * 32 + mf * 16 + g * 4;
#pragma unroll
            for (int r = 0; r < 4; r++)
                fvb[((size_t)((b * 128 + y) * 128 + xp + r)) * 96 + co] = f2bf(acc[mf][f][r] + bb);
        }
    }
}

// ---- FUSED patch+attn: 1024 blocks, 2x 64-px chunks ----
__global__ __launch_bounds__(256) void k_pattn2(
        const float* __restrict__ fq, const float* __restrict__ fk,
        u16* __restrict__ f1w, float* __restrict__ part) {
    __shared__ float qs[96 * 65];
    __shared__ float ks[96 * 65];
    int wg = ((blockIdx.x & 7) << 7) | (blockIdx.x >> 3);   // XCD swizzle
    int b = wg >> 7, ys = (wg >> 2) & 31, xq = wg & 3;
    int y0 = ys * 4, x0 = xq * 32;
    int tx = threadIdx.x & 15, ty = threadIdx.x >> 4;
    double accD[6][6];
#pragma unroll
    for (int a = 0; a < 6; a++)
#pragma unroll
        for (int bb = 0; bb < 6; bb++) accD[a][bb] = 0.0;
#pragma unroll
    for (int cx = 0; cx < 2; cx++) {
        for (int idx = threadIdx.x; idx < 1536; idx += 256) {
            int p = idx / 24, c0 = (idx - p * 24) * 4;
            int ry = p >> 4, rx = p & 15;
            size_t off = ((size_t)((b * 128 + y0 + ry) * 128 + x0 + cx * 16 + rx)) * 96 + c0;
            f32x4 qv = *(const f32x4*)(fq + off);
            f32x4 kv = *(const f32x4*)(fk + off);
#pragma unroll
            for (int u = 0; u < 4; u++) {
                qs[(c0 + u) * 65 + p] = qv[u];
                ks[(c0 + u) * 65 + p] = kv[u];
            }
        }
        __syncthreads();
        for (int item = threadIdx.x; item < 384; item += 256) {
            int j = item / 96, c = item - j * 96;
            float A[4][4], Bm[4][4];
#pragma unroll
            for (int r = 0; r < 4; r++)
#pragma unroll
                for (int m = 0; m < 4; m++) {
                    A[r][m] = qs[c * 65 + r * 16 + j * 4 + m];
                    Bm[r][m] = ks[c * 65 + r * 16 + j * 4 + m];
                }
            float rsB[4], csB[4], rsA[4], tot = 0.f;
#pragma unroll
            for (int r = 0; r < 4; r++) {
                rsB[r] = Bm[r][0] + Bm[r][1] + Bm[r][2] + Bm[r][3];
                rsA[r] = A[r][0] + A[r][1] + A[r][2] + A[r][3];
                tot += rsB[r];
            }
#pragma unroll
            for (int m = 0; m < 4; m++) csB[m] = Bm[0][m] + Bm[1][m] + Bm[2][m] + Bm[3][m];
#pragma unroll
            for (int r = 0; r < 4; r++)
#pragma unroll
                for (int m = 0; m < 4; m++) {
                    float ab = A[r][0] * Bm[0][m] + A[r][1] * Bm[1][m]
                             + A[r][2] * Bm[2][m] + A[r][3] * Bm[3][m];
                    f1w[((size_t)((b * 128 + y0 + r) * 128 + x0 + cx * 16 + j * 4 + m)) * 96 + c]
                        = f2bf(8.f * ab + 2.f * rsA[r] * csB[m]);
                }
#pragma unroll
            for (int r = 0; r < 4; r++)
#pragma unroll
                for (int m = 0; m < 4; m++)
                    ks[c * 65 + r * 16 + j * 4 + m]
                        = 64.f * Bm[r][m] + 16.f * (rsB[r] + csB[m]) + 4.f * tot;
        }
        __syncthreads();
        float acc[6][6];
#pragma unroll
        for (int a = 0; a < 6; a++)
#pragma unroll
            for (int bb = 0; bb < 6; bb++) acc[a][bb] = 0.f;
        for (int l = 0; l < 64; l++) {
            float qv[6], kv[6];
#pragma unroll
            for (int a = 0; a < 6; a++) qv[a] = qs[(ty + 16 * a) * 65 + l];
#pragma unroll
            for (int bb = 0; bb < 6; bb++) kv[bb] = ks[(tx + 16 * bb) * 65 + l];
#pragma unroll
            for (int a = 0; a < 6; a++)
#pragma unroll
                for (int bb = 0; bb < 6; bb++) acc[a][bb] += qv[a] * kv[bb];
        }
#pragma unroll
        for (int a = 0; a < 6; a++)
#pragma unroll
            for (int bb = 0; bb < 6; bb++) accD[a][bb] += (double)acc[a][bb];
        __syncthreads();
    }
    int s128 = ys * 4 + xq;
#pragma unroll
    for (int a = 0; a < 6; a++)
#pragma unroll
        for (int bb = 0; bb < 6; bb++)
            part[((size_t)((b * 128 + s128) * 96 + ty + 16 * a)) * 96 + tx + 16 * bb]
                = (float)accD[a][bb];
}

// ---- reduce 128 slices (f64) + temperature + row softmax -> bf16 weights ----
__global__ __launch_bounds__(128) void k_softmax(
        const float* __restrict__ part, const float* __restrict__ temp,
        u16* __restrict__ attnb) {
    __shared__ float red[128];
    int b = blockIdx.x / 96, i2 = blockIdx.x - b * 96;
    int j2 = threadIdx.x;
    float v = 0.f;
    if (j2 < 96) {
        double vd = 0.0;
        for (int s = 0; s < 128; s++)
            vd += (double)part[((size_t)((b * 128 + s) * 96 + i2)) * 96 + j2];
        v = (float)vd * temp[0];
    }
    red[j2] = (j2 < 96) ? v : -3.4e38f;
    __syncthreads();
    for (int off = 64; off >= 1; off >>= 1) {
        if (j2 < off) red[j2] = fmaxf(red[j2], red[j2 + off]);
        __syncthreads();
    }
    float mx = red[0];
    __syncthreads();
    float e = (j2 < 96) ? expf(v - mx) : 0.f;
    red[j2] = e;
    __syncthreads();
    for (int off = 64; off >= 1; off >>= 1) {
        if (j2 < off) red[j2] += red[j2 + off];
        __syncthreads();
    }
    float sum = red[0];
    if (j2 < 96) attnb[((size_t)(b * 96) + i2) * 96 + j2] = f2bf(e / sum);
}

// ---- Gt = (F_Q - 0.5 F_V)^T, Fvn = F_V, both bf16 [B][C][.][.] ----
__global__ __launch_bounds__(256) void k_gprep(
        const float* __restrict__ fqn, const u16* __restrict__ fvb,
        u16* __restrict__ gt, u16* __restrict__ fvn) {
    __shared__ u16 lg[8 * 32 * 33];
    __shared__ u16 lv[8 * 32 * 33];
    int blk = blockIdx.x;
    int b = blk / 192;
    int r = blk - b * 192;
    int yt = r / 48; r -= yt * 48;
    int xt = r / 12; int cc = r - xt * 12;
    int y0 = yt * 32, x0 = xt * 32, c0 = cc * 8;
    for (int idx = threadIdx.x; idx < 8192; idx += 256) {
        int pix = idx >> 3, cl = idx & 7;
        int yy = pix >> 5, xx = pix & 31;
        size_t off = ((size_t)((b * 128 + y0 + yy) * 128 + x0 + xx)) * 96 + c0 + cl;
        float q = fqn[off];
        float v = bf2f(fvb[off]);
        int la = (cl * 32 + yy) * 33 + xx;
        lg[la] = f2bf(q - 0.5f * v);
        lv[la] = f2bf(v);
    }
    __syncthreads();
    for (int idx = threadIdx.x; idx < 8192; idx += 256) {
        int yy = idx & 31, xl = (idx >> 5) & 31, cl = idx >> 10;
        gt[((size_t)((b * 96 + c0 + cl) * 128 + x0 + xl)) * 128 + y0 + yy] = lg[(cl * 32 + yy) * 33 + xl];
    }
    for (int idx = threadIdx.x; idx < 8192; idx += 256) {
        int xx = idx & 31, yl = (idx >> 5) & 31, cl = idx >> 10;
        fvn[((size_t)((b * 96 + c0 + cl) * 128 + y0 + yl)) * 128 + x0 + xx] = lv[(cl * 32 + yl) * 33 + xx];
    }
}

// ---- FCFR[b][i][pix] = sum_j attn[i][j] * F1W[b][pix][j]  (bf16 MFMA) ----
__global__ __launch_bounds__(256) void k_fcfr2(
        const u16* __restrict__ attnb, const u16* __restrict__ f1w,
        u16* __restrict__ fc) {
    int b = blockIdx.x >> 6, pc = blockIdx.x & 63;
    int lane = threadIdx.x & 63, wv_ = threadIdx.x >> 6;
    int l15 = lane & 15, g = lane >> 4;
    int pbase = pc * 256 + wv_ * 64;
    f32x4 acc[6][4];
#pragma unroll
    for (int m = 0; m < 6; m++)
#pragma unroll
        for (int n = 0; n < 4; n++) acc[m][n] = (f32x4){0.f, 0.f, 0.f, 0.f};
#pragma unroll
    for (int ks = 0; ks < 3; ks++) {
        int k0 = ks * 32 + g * 8;
        i32x4 afr[6];
#pragma unroll
        for (int m = 0; m < 6; m++)
            afr[m] = *(const i32x4*)(attnb + ((size_t)(b * 96 + m * 16 + l15)) * 96 + k0);
#pragma unroll
        for (int n = 0; n < 4; n++) {
            i32x4 bfr = *(const i32x4*)(f1w + ((size_t)(b * 16384 + pbase + n * 16 + l15)) * 96 + k0);
#pragma unroll
            for (int m = 0; m < 6; m++)
                acc[m][n] = mfma16(afr[m], bfr, acc[m][n]);
        }
    }
#pragma unroll
    for (int m = 0; m < 6; m++)
#pragma unroll
        for (int n = 0; n < 4; n++)
#pragma unroll
            for (int r = 0; r < 4; r++) {
                int i2 = m * 16 + g * 4 + r;
                int pix = pbase + n * 16 + l15;
                fc[((size_t)(b * 96 + i2)) * HWSZ + pix] = f2bf(acc[m][n][r]);
            }
}

// ---- out = Fcfrout @ (F_Q - 0.5 F_V) + F_V  (bf16 MFMA, per (b,c) 128^3) ----
__global__ __launch_bounds__(256) void k_final(
        const u16* __restrict__ fc, const u16* __restrict__ gt,
        const u16* __restrict__ fvn, float* __restrict__ out) {
    int b = blockIdx.x / 96, c = blockIdx.x - b * 96;
    int lane = threadIdx.x & 63, wv_ = threadIdx.x >> 6;
    int l15 = lane & 15, g = lane >> 4;
    const u16* A = fc + ((size_t)(b * 96 + c)) * HWSZ;
    const u16* Bm = gt + ((size_t)(b * 96 + c)) * HWSZ;
    f32x4 acc[2][8];
#pragma unroll
    for (int mf = 0; mf < 2; mf++)
#pragma unroll
        for (int nf = 0; nf < 8; nf++) acc[mf][nf] = (f32x4){0.f, 0.f, 0.f, 0.f};
#pragma unroll
    for (int kc = 0; kc < 4; kc++) {
        int k0 = kc * 32 + g * 8;
        i32x4 af[2];
#pragma unroll
        for (int mf = 0; mf < 2; mf++)
            af[mf] = *(const i32x4*)(A + (size_t)(wv_ * 32 + mf * 16 + l15) * 128 + k0);
#pragma unroll
        for (int nf = 0; nf < 8; nf++) {
            i32x4 bf = *(const i32x4*)(Bm + (size_t)(nf * 16 + l15) * 128 + k0);
#pragma unroll
            for (int mf = 0; mf < 2; mf++)
                acc[mf][nf] = mfma16(af[mf], bf, acc[mf][nf]);
        }
    }
    const u16* V = fvn + ((size_t)(b * 96 + c)) * HWSZ;
    float* O = out + ((size_t)(b * 96 + c)) * HWSZ;
#pragma unroll
    for (int mf = 0; mf < 2; mf++)
#pragma unroll
        for (int nf = 0; nf < 8; nf++)
#pragma unroll
            for (int r = 0; r < 4; r++) {
                int y = wv_ * 32 + mf * 16 + g * 4 + r;
                int x = nf * 16 + l15;
                O[y * 128 + x] = acc[mf][nf][r] + bf2f(V[y * 128 + x]);
            }
}

extern "C" void kernel_launch(void* const* d_in, const int* in_sizes, int n_in,
                              void* d_out, int out_size, void* d_ws, size_t ws_size,
                              hipStream_t stream) {
    (void)in_sizes; (void)n_in;
    if (ws_size < (size_t)WS_NEED) {
        k_diag<<<2048, 256, 0, stream>>>((float*)d_out, out_size, (float)(ws_size >> 10));
        return;
    }
    const float* in1 = (const float*)d_in[0];
    const float* in2 = (const float*)d_in[1];
    const float* wq  = (const float*)d_in[2];
    const float* bq  = (const float*)d_in[3];
    const float* wk  = (const float*)d_in[4];
    const float* bk  = (const float*)d_in[5];
    const float* wv  = (const float*)d_in[6];
    const float* bv  = (const float*)d_in[7];
    const float* temp = (const float*)d_in[8];
    char* ws = (char*)d_ws;
    float* FQ   = (float*)(ws + OFF_FQ);
    float* FK   = (float*)(ws + OFF_FK);
    u16*  GT    = (u16*)(ws + OFF_GT);
    u16*  FVN   = (u16*)(ws + OFF_FVN);
    u16*  PAD1H = (u16*)(ws + OFF_PAD1H);
    u16*  PAD1L = (u16*)(ws + OFF_PAD1L);
    u16*  PAD2  = (u16*)(ws + OFF_PAD2);
    u16*  F1W   = (u16*)(ws + OFF_F1W);
    float* PART = (float*)(ws + OFF_PART);
    u16*  FCFR  = (u16*)(ws + OFF_FCFR);
    u16*  FVB   = (u16*)(ws + OFF_FVB);
    u16*  ATTNB = (u16*)(ws + OFF_ATTNB);
    u16*  WQK   = (u16*)(ws + OFF_WQK);
    u16*  WV    = (u16*)(ws + OFF_WV);

    k_zhalo<<<24, 256, 0, stream>>>(PAD1H);
    k_trans2<<<2048, 256, 0, stream>>>(in1, in2, PAD1H, PAD1L, PAD2);
    k_weights_all<<<288, 128, 0, stream>>>(wq, wk, wv, WQK, WV);
    k_convqk6<<<1024, 512, 0, stream>>>(PAD1H, PAD1L, WQK, bq, bk, FQ, FK);
    k_convv6<<<1024, 512, 0, stream>>>(PAD2, WV, bv, FVB);
    k_pattn2<<<1024, 256, 0, stream>>>(FQ, FK, F1W, PART);
    k_softmax<<<768, 128, 0, stream>>>(PART, temp, ATTNB);
    k_gprep<<<1536, 256, 0, stream>>>(FQ, FVB, GT, FVN);
    k_fcfr2<<<512, 256, 0, stream>>>(ATTNB, F1W, FCFR);
    k_final<<<768, 256, 0, stream>>>(FCFR, GT, FVN, (float*)d_out);
}

// Round 17
// 375.164 us; speedup vs baseline: 1.0677x; 1.0102x over previous
//
#include <hip/hip_runtime.h>

typedef unsigned short u16;
typedef unsigned int u32;
typedef __bf16 bf16x8 __attribute__((ext_vector_type(8)));
typedef float f32x4 __attribute__((ext_vector_type(4)));
typedef int i32x4 __attribute__((ext_vector_type(4)));

#define BATCH 8
#define CH 96
#define HWSZ 16384
#define PADP (130*130*96)   // elems per padded plane-image
#define LSTR 68             // padded LDS row stride (68*4B = 272B, 16B-aligned cols)

// ---- workspace layout (bytes) ----
#define OFF_FQ     0ULL          // f32 NHWC (convqk..gprep)
#define OFF_FK     50331648ULL   // f32 NHWC (convqk..pattn); then:
#define OFF_GT     50331648ULL   //   bf16 [B][C][x][y] (gprep..final)
#define OFF_FVN    75497472ULL   //   bf16 [B][C][y][x] (gprep..final)
#define OFF_PAD1H  100663296ULL  // bf16 padded (trans..convqk) 25958400
#define OFF_F1W    100663296ULL  //   bf16 NHWC F1tilde (pattn..fcfr2)
#define OFF_PART   126621696ULL  // f32 [B][128][96][96] 37.75MB (pattn..softmax)
#define OFF_PAD1L  126621696ULL  // bf16 padded (trans..convqk)
#define OFF_PAD2   152580096ULL  // bf16 padded (trans..convv)
#define OFF_FCFR   152580096ULL  //   bf16 [B][C][y][x] (fcfr2..final)
#define OFF_FVB    178538496ULL  // bf16 NHWC (convv..gprep)
#define OFF_ATTNB  203704320ULL  // bf16 [B][96][96]
#define OFF_WQK    203851776ULL  // bf16 packed [27][plane2][g4][co192][8]: 663552B
#define OFF_WV     204515328ULL  // bf16 packed [27][4][96][8]: 165888
#define WS_NEED    204681216ULL

__device__ __forceinline__ u16 f2bf(float f) {
    u32 u = __builtin_bit_cast(u32, f);
    u += 0x7fffu + ((u >> 16) & 1u);
    return (u16)(u >> 16);
}
__device__ __forceinline__ float bf2f(u16 h) {
    u32 u = ((u32)h) << 16;
    return __builtin_bit_cast(float, u);
}
__device__ __forceinline__ f32x4 mfma16(i32x4 a, i32x4 b, f32x4 c) {
    return __builtin_amdgcn_mfma_f32_16x16x32_bf16(
        __builtin_bit_cast(bf16x8, a), __builtin_bit_cast(bf16x8, b), c, 0, 0, 0);
}
__device__ __forceinline__ void gl_lds16(const u16* g, u16* l) {
    __builtin_amdgcn_global_load_lds(
        (const __attribute__((address_space(1))) unsigned int*)g,
        (__attribute__((address_space(3))) unsigned int*)l, 16, 0, 0);
}

__global__ __launch_bounds__(256) void k_diag(float* __restrict__ out, int n, float val) {
    for (int i = blockIdx.x * 256 + threadIdx.x; i < n; i += gridDim.x * 256) out[i] = val;
}

// ---- zero halo of the 3 contiguous padded planes (24 images) ----
__global__ __launch_bounds__(256) void k_zhalo(u16* __restrict__ p) {
    size_t base = (size_t)blockIdx.x * PADP;
    for (int i = threadIdx.x; i < 130 * 96; i += 256) {
        p[base + i] = 0;
        p[base + (size_t)129 * 130 * 96 + i] = 0;
    }
    for (int i = threadIdx.x; i < 128 * 2 * 96; i += 256) {
        int row = i / 192, k = i - row * 192;
        int x = (k < 96) ? 0 : 129, c = (k < 96) ? k : k - 96;
        p[base + ((size_t)(row + 1) * 130 + x) * 96 + c] = 0;
    }
}

// ---- both inputs: NCHW f32 -> padded NHWC bf16 (in1: hi+lo, in2: hi) ----
__global__ __launch_bounds__(256) void k_trans2(const float* __restrict__ in1,
        const float* __restrict__ in2, u16* __restrict__ p1h, u16* __restrict__ p1l,
        u16* __restrict__ p2) {
    __shared__ float tile[96][129];
    int which = blockIdx.x >> 10;
    int blk = blockIdx.x & 1023;
    const float* src = which ? in2 : in1;
    u16* dh = which ? p2 : p1h;
    u16* dl = which ? nullptr : p1l;
    int b = blk >> 7, y = blk & 127;
    const float* s = src + (size_t)b * CH * HWSZ + (size_t)y * 128;
    for (int idx = threadIdx.x; idx < CH * 128; idx += 256) {
        int c = idx >> 7, x = idx & 127;
        tile[c][x] = s[(size_t)c * HWSZ + x];
    }
    __syncthreads();
    size_t obase = ((size_t)(b * 130 + y + 1) * 130 + 1) * 96;
    for (int idx = threadIdx.x; idx < 128 * CH; idx += 256) {
        int x = idx / CH, c = idx - x * CH;
        float v = tile[c][x];
        u16 h = f2bf(v);
        dh[obase + idx] = h;
        if (dl) dl[obase + idx] = f2bf(v - bf2f(h));
    }
}

// ---- weights: QK -> [s=cic*9+tap][plane][g][co192][8] hi/lo; V -> [s][g][96][8] ----
__global__ __launch_bounds__(128) void k_weights_all(const float* __restrict__ wq,
        const float* __restrict__ wk, const float* __restrict__ wv,
        u16* __restrict__ dqk, u16* __restrict__ dv) {
    int co = blockIdx.x;  // 0..287
    if (co < 192) {
        const float* w = (co < 96) ? wq : wk;
        int cs = (co < 96) ? co : co - 96;
        for (int idx = threadIdx.x; idx < 864; idx += 128) {
            int tap = idx / 96, ci = idx - tap * 96;
            int cic = ci >> 5, g = (ci >> 3) & 3, c7 = ci & 7;
            float v = w[((size_t)cs * 96 + ci) * 9 + tap];
            u16 h = f2bf(v), lo = f2bf(v - bf2f(h));
            size_t s = (size_t)(cic * 9 + tap);
            dqk[(((s * 2 + 0) * 4 + g) * 192 + co) * 8 + c7] = h;
            dqk[(((s * 2 + 1) * 4 + g) * 192 + co) * 8 + c7] = lo;
        }
    } else {
        int cs = co - 192;
        for (int idx = threadIdx.x; idx < 864; idx += 128) {
            int tap = idx / 96, ci = idx - tap * 96;
            int cic = ci >> 5, g = (ci >> 3) & 3, c7 = ci & 7;
            float v = wv[((size_t)cs * 96 + ci) * 9 + tap];
            size_t s = (size_t)(cic * 9 + tap);
            dv[((s * 4 + g) * 96 + cs) * 8 + c7] = f2bf(v);
        }
    }
}

// ---- fused Q+K conv: round-9 champion, single full-grid launch ----
__global__ __launch_bounds__(512, 4) void k_convqk6(
        const u16* __restrict__ ph, const u16* __restrict__ pl,
        const u16* __restrict__ wqk,
        const float* __restrict__ bq, const float* __restrict__ bk,
        float* __restrict__ fq, float* __restrict__ fk) {
    __shared__ u16 wbuf[2][12288];
    const int tid = threadIdx.x;
    const int wg = ((blockIdx.x & 7) << 7) | (blockIdx.x >> 3);  // XCD swizzle: 1 image/XCD
    const int b = wg >> 7, y = wg & 127;
    const int w = tid >> 6, lane = tid & 63, l15 = lane & 15, g = lane >> 4;
    const int wx = w & 3, wc = w >> 2;
    f32x4 acc[2][6];
#pragma unroll
    for (int mf = 0; mf < 2; mf++)
#pragma unroll
        for (int f = 0; f < 6; f++) acc[mf][f] = (f32x4){0.f, 0.f, 0.f, 0.f};
    {
#pragma unroll
        for (int j = 0; j < 3; j++)
            gl_lds16(wqk + (size_t)(tid + j * 512) * 8, &wbuf[0][(size_t)(tid + j * 512) * 8]);
    }
    i32x4 ah0, ah1, al0, al1;
    {
        size_t ab = ((size_t)(b * 130 + y) * 130 + (wx * 32 + l15)) * 96 + g * 8;
        ah0 = *(const i32x4*)(ph + ab);
        ah1 = *(const i32x4*)(ph + ab + 16 * 96);
        al0 = *(const i32x4*)(pl + ab);
        al1 = *(const i32x4*)(pl + ab + 16 * 96);
    }
    __syncthreads();
    for (int s = 0; s < 27; s++) {
        const int cur = s & 1;
        i32x4 nh0, nh1, nl0, nl1;
        if (s + 1 < 27) {
            const u16* src = wqk + (size_t)(s + 1) * 12288;
#pragma unroll
            for (int j = 0; j < 3; j++)
                gl_lds16(src + (size_t)(tid + j * 512) * 8, &wbuf[cur ^ 1][(size_t)(tid + j * 512) * 8]);
            const int s1 = s + 1;
            const int cic1 = s1 / 9, tap1 = s1 - cic1 * 9;
            const int dy1 = tap1 / 3 - 1, dx1 = tap1 - (tap1 / 3) * 3 - 1;
            size_t ab = ((size_t)(b * 130 + y + 1 + dy1) * 130 + (wx * 32 + l15 + 1 + dx1)) * 96
                      + cic1 * 32 + g * 8;
            nh0 = *(const i32x4*)(ph + ab);
            nh1 = *(const i32x4*)(ph + ab + 16 * 96);
            nl0 = *(const i32x4*)(pl + ab);
            nl1 = *(const i32x4*)(pl + ab + 16 * 96);
        }
#pragma unroll
        for (int f = 0; f < 6; f++) {
            const int cob = wc * 96 + f * 16 + l15;
            i32x4 bh = *(const i32x4*)(&wbuf[cur][((0 + g) * 192 + cob) * 8]);
            i32x4 bl = *(const i32x4*)(&wbuf[cur][((4 + g) * 192 + cob) * 8]);
            acc[0][f] = mfma16(ah0, bh, acc[0][f]);
            acc[0][f] = mfma16(ah0, bl, acc[0][f]);
            acc[0][f] = mfma16(al0, bh, acc[0][f]);
            acc[1][f] = mfma16(ah1, bh, acc[1][f]);
            acc[1][f] = mfma16(ah1, bl, acc[1][f]);
            acc[1][f] = mfma16(al1, bh, acc[1][f]);
        }
        __syncthreads();
        if (s + 1 < 27) { ah0 = nh0; ah1 = nh1; al0 = nl0; al1 = nl1; }
    }
    const float* bias = wc ? bk : bq;
    float* op = wc ? fk : fq;
#pragma unroll
    for (int f = 0; f < 6; f++) {
        const int co = f * 16 + l15;
        const float bb = bias[co];
#pragma unroll
        for (int mf = 0; mf < 2; mf++) {
            const int xp = wx * 32 + mf * 16 + g * 4;
#pragma unroll
            for (int r = 0; r < 4; r++)
                op[((size_t)((b * 128 + y) * 128 + xp + r)) * 96 + co] = acc[mf][f][r] + bb;
        }
    }
}

// ---- V conv: round-9 structure ----
__global__ __launch_bounds__(512, 4) void k_convv6(
        const u16* __restrict__ p2, const u16* __restrict__ wv,
        const float* __restrict__ bv, u16* __restrict__ fvb) {
    __shared__ u16 vbuf[2][3072];
    const int tid = threadIdx.x;
    const int wg = ((blockIdx.x & 7) << 7) | (blockIdx.x >> 3);
    const int b = wg >> 7, y = wg & 127;
    const int w = tid >> 6, lane = tid & 63, l15 = lane & 15, g = lane >> 4;
    const int wx = w & 3, wc = w >> 2;
    f32x4 acc[2][3];
#pragma unroll
    for (int mf = 0; mf < 2; mf++)
#pragma unroll
        for (int f = 0; f < 3; f++) acc[mf][f] = (f32x4){0.f, 0.f, 0.f, 0.f};
    if (tid < 384)
        gl_lds16(wv + (size_t)tid * 8, &vbuf[0][(size_t)tid * 8]);
    i32x4 ah0, ah1;
    {
        size_t ab = ((size_t)(b * 130 + y) * 130 + (wx * 32 + l15)) * 96 + g * 8;
        ah0 = *(const i32x4*)(p2 + ab);
        ah1 = *(const i32x4*)(p2 + ab + 16 * 96);
    }
    __syncthreads();
    for (int s = 0; s < 27; s++) {
        const int cur = s & 1;
        i32x4 nh0, nh1;
        if (s + 1 < 27) {
            if (tid < 384)
                gl_lds16(wv + (size_t)(s + 1) * 3072 + (size_t)tid * 8, &vbuf[cur ^ 1][(size_t)tid * 8]);
            const int s1 = s + 1;
            const int cic1 = s1 / 9, tap1 = s1 - cic1 * 9;
            const int dy1 = tap1 / 3 - 1, dx1 = tap1 - (tap1 / 3) * 3 - 1;
            size_t ab = ((size_t)(b * 130 + y + 1 + dy1) * 130 + (wx * 32 + l15 + 1 + dx1)) * 96
                      + cic1 * 32 + g * 8;
            nh0 = *(const i32x4*)(p2 + ab);
            nh1 = *(const i32x4*)(p2 + ab + 16 * 96);
        }
#pragma unroll
        for (int f = 0; f < 3; f++) {
            const int cof = wc * 48 + f * 16 + l15;
            i32x4 bfr = *(const i32x4*)(&vbuf[cur][(g * 96 + cof) * 8]);
            acc[0][f] = mfma16(ah0, bfr, acc[0][f]);
            acc[1][f] = mfma16(ah1, bfr, acc[1][f]);
        }
        __syncthreads();
        if (s + 1 < 27) { ah0 = nh0; ah1 = nh1; }
    }
#pragma unroll
    for (int f = 0; f < 3; f++) {
        const int co = wc * 48 + f * 16 + l15;
        const float bb = bv[co];
#pragma unroll
        for (int mf = 0; mf < 2; mf++) {
            const int xp = wx * 32 + mf * 16 + g * 4;
#pragma unroll
            for (int r = 0; r < 4; r++)
                fvb[((size_t)((b * 128 + y) * 128 + xp + r)) * 96 + co] = f2bf(acc[mf][f][r] + bb);
        }
    }
}

// ---- FUSED patch+attn: 1024 blocks, 2x 64-px chunks, VECTORIZED LDS access ----
__global__ __launch_bounds__(256) void k_pattn2(
        const float* __restrict__ fq, const float* __restrict__ fk,
        u16* __restrict__ f1w, float* __restrict__ part) {
    __shared__ __attribute__((aligned(16))) float qs[96 * LSTR];
    __shared__ __attribute__((aligned(16))) float ks[96 * LSTR];
    int wg = ((blockIdx.x & 7) << 7) | (blockIdx.x >> 3);   // XCD swizzle
    int b = wg >> 7, ys = (wg >> 2) & 31, xq = wg & 3;
    int y0 = ys * 4, x0 = xq * 32;
    int tx = threadIdx.x & 15, ty = threadIdx.x >> 4;
    double accD[6][6];
#pragma unroll
    for (int a = 0; a < 6; a++)
#pragma unroll
        for (int bb = 0; bb < 6; bb++) accD[a][bb] = 0.0;
#pragma unroll
    for (int cx = 0; cx < 2; cx++) {
        // stage 64 px (4 rows x 16 cols) x 96 c
        for (int idx = threadIdx.x; idx < 1536; idx += 256) {
            int p = idx / 24, c0 = (idx - p * 24) * 4;
            int ry = p >> 4, rx = p & 15;
            size_t off = ((size_t)((b * 128 + y0 + ry) * 128 + x0 + cx * 16 + rx)) * 96 + c0;
            f32x4 qv = *(const f32x4*)(fq + off);
            f32x4 kv = *(const f32x4*)(fk + off);
#pragma unroll
            for (int u = 0; u < 4; u++) {
                qs[(c0 + u) * LSTR + p] = qv[u];
                ks[(c0 + u) * LSTR + p] = kv[u];
            }
        }
        __syncthreads();
        // patch phase: 4 x-patches x 96 c = 384 items (f32x4 reads/writes over m)
        for (int item = threadIdx.x; item < 384; item += 256) {
            int j = item / 96, c = item - j * 96;
            f32x4 A[4], Bm[4];
#pragma unroll
            for (int r = 0; r < 4; r++) {
                A[r]  = *(const f32x4*)&qs[c * LSTR + r * 16 + j * 4];
                Bm[r] = *(const f32x4*)&ks[c * LSTR + r * 16 + j * 4];
            }
            float rsB[4], csB[4], rsA[4], tot = 0.f;
#pragma unroll
            for (int r = 0; r < 4; r++) {
                rsB[r] = Bm[r][0] + Bm[r][1] + Bm[r][2] + Bm[r][3];
                rsA[r] = A[r][0] + A[r][1] + A[r][2] + A[r][3];
                tot += rsB[r];
            }
#pragma unroll
            for (int m = 0; m < 4; m++) csB[m] = Bm[0][m] + Bm[1][m] + Bm[2][m] + Bm[3][m];
#pragma unroll
            for (int r = 0; r < 4; r++) {
#pragma unroll
                for (int m = 0; m < 4; m++) {
                    float ab = A[r][0] * Bm[0][m] + A[r][1] * Bm[1][m]
                             + A[r][2] * Bm[2][m] + A[r][3] * Bm[3][m];
                    f1w[((size_t)((b * 128 + y0 + r) * 128 + x0 + cx * 16 + j * 4 + m)) * 96 + c]
                        = f2bf(8.f * ab + 2.f * rsA[r] * csB[m]);
                }
                f32x4 kt;
#pragma unroll
                for (int m = 0; m < 4; m++)
                    kt[m] = 64.f * Bm[r][m] + 16.f * (rsB[r] + csB[m]) + 4.f * tot;
                *(f32x4*)&ks[c * LSTR + r * 16 + j * 4] = kt;
            }
        }
        __syncthreads();
        // dot phase: vectorized over l (16 groups of 4)
        float acc[6][6];
#pragma unroll
        for (int a = 0; a < 6; a++)
#pragma unroll
            for (int bb = 0; bb < 6; bb++) acc[a][bb] = 0.f;
        for (int l4 = 0; l4 < 16; l4++) {
            f32x4 qv4[6], kv4[6];
#pragma unroll
            for (int a = 0; a < 6; a++)
                qv4[a] = *(const f32x4*)&qs[(ty + 16 * a) * LSTR + l4 * 4];
#pragma unroll
            for (int bb = 0; bb < 6; bb++)
                kv4[bb] = *(const f32x4*)&ks[(tx + 16 * bb) * LSTR + l4 * 4];
#pragma unroll
            for (int a = 0; a < 6; a++)
#pragma unroll
                for (int bb = 0; bb < 6; bb++) {
                    acc[a][bb] += qv4[a][0] * kv4[bb][0];
                    acc[a][bb] += qv4[a][1] * kv4[bb][1];
                    acc[a][bb] += qv4[a][2] * kv4[bb][2];
                    acc[a][bb] += qv4[a][3] * kv4[bb][3];
                }
        }
#pragma unroll
        for (int a = 0; a < 6; a++)
#pragma unroll
            for (int bb = 0; bb < 6; bb++) accD[a][bb] += (double)acc[a][bb];
        __syncthreads();
    }
    int s128 = ys * 4 + xq;
#pragma unroll
    for (int a = 0; a < 6; a++)
#pragma unroll
        for (int bb = 0; bb < 6; bb++)
            part[((size_t)((b * 128 + s128) * 96 + ty + 16 * a)) * 96 + tx + 16 * bb]
                = (float)accD[a][bb];
}

// ---- reduce 128 slices (f64) + temperature + row softmax -> bf16 weights ----
__global__ __launch_bounds__(128) void k_softmax(
        const float* __restrict__ part, const float* __restrict__ temp,
        u16* __restrict__ attnb) {
    __shared__ float red[128];
    int b = blockIdx.x / 96, i2 = blockIdx.x - b * 96;
    int j2 = threadIdx.x;
    float v = 0.f;
    if (j2 < 96) {
        double vd = 0.0;
        for (int s = 0; s < 128; s++)
            vd += (double)part[((size_t)((b * 128 + s) * 96 + i2)) * 96 + j2];
        v = (float)vd * temp[0];
    }
    red[j2] = (j2 < 96) ? v : -3.4e38f;
    __syncthreads();
    for (int off = 64; off >= 1; off >>= 1) {
        if (j2 < off) red[j2] = fmaxf(red[j2], red[j2 + off]);
        __syncthreads();
    }
    float mx = red[0];
    __syncthreads();
    float e = (j2 < 96) ? expf(v - mx) : 0.f;
    red[j2] = e;
    __syncthreads();
    for (int off = 64; off >= 1; off >>= 1) {
        if (j2 < off) red[j2] += red[j2 + off];
        __syncthreads();
    }
    float sum = red[0];
    if (j2 < 96) attnb[((size_t)(b * 96) + i2) * 96 + j2] = f2bf(e / sum);
}

// ---- Gt = (F_Q - 0.5 F_V)^T, Fvn = F_V, both bf16 [B][C][.][.] ----
__global__ __launch_bounds__(256) void k_gprep(
        const float* __restrict__ fqn, const u16* __restrict__ fvb,
        u16* __restrict__ gt, u16* __restrict__ fvn) {
    __shared__ u16 lg[8 * 32 * 33];
    __shared__ u16 lv[8 * 32 * 33];
    int blk = blockIdx.x;
    int b = blk / 192;
    int r = blk - b * 192;
    int yt = r / 48; r -= yt * 48;
    int xt = r / 12; int cc = r - xt * 12;
    int y0 = yt * 32, x0 = xt * 32, c0 = cc * 8;
    for (int idx = threadIdx.x; idx < 8192; idx += 256) {
        int pix = idx >> 3, cl = idx & 7;
        int yy = pix >> 5, xx = pix & 31;
        size_t off = ((size_t)((b * 128 + y0 + yy) * 128 + x0 + xx)) * 96 + c0 + cl;
        float q = fqn[off];
        float v = bf2f(fvb[off]);
        int la = (cl * 32 + yy) * 33 + xx;
        lg[la] = f2bf(q - 0.5f * v);
        lv[la] = f2bf(v);
    }
    __syncthreads();
    for (int idx = threadIdx.x; idx < 8192; idx += 256) {
        int yy = idx & 31, xl = (idx >> 5) & 31, cl = idx >> 10;
        gt[((size_t)((b * 96 + c0 + cl) * 128 + x0 + xl)) * 128 + y0 + yy] = lg[(cl * 32 + yy) * 33 + xl];
    }
    for (int idx = threadIdx.x; idx < 8192; idx += 256) {
        int xx = idx & 31, yl = (idx >> 5) & 31, cl = idx >> 10;
        fvn[((size_t)((b * 96 + c0 + cl) * 128 + y0 + yl)) * 128 + x0 + xx] = lv[(cl * 32 + yl) * 33 + xx];
    }
}

// ---- FCFR[b][i][pix] = sum_j attn[i][j] * F1W[b][pix][j]  (bf16 MFMA) ----
__global__ __launch_bounds__(256) void k_fcfr2(
        const u16* __restrict__ attnb, const u16* __restrict__ f1w,
        u16* __restrict__ fc) {
    int b = blockIdx.x >> 6, pc = blockIdx.x & 63;
    int lane = threadIdx.x & 63, wv_ = threadIdx.x >> 6;
    int l15 = lane & 15, g = lane >> 4;
    int pbase = pc * 256 + wv_ * 64;
    f32x4 acc[6][4];
#pragma unroll
    for (int m = 0; m < 6; m++)
#pragma unroll
        for (int n = 0; n < 4; n++) acc[m][n] = (f32x4){0.f, 0.f, 0.f, 0.f};
#pragma unroll
    for (int ks = 0; ks < 3; ks++) {
        int k0 = ks * 32 + g * 8;
        i32x4 afr[6];
#pragma unroll
        for (int m = 0; m < 6; m++)
            afr[m] = *(const i32x4*)(attnb + ((size_t)(b * 96 + m * 16 + l15)) * 96 + k0);
#pragma unroll
        for (int n = 0; n < 4; n++) {
            i32x4 bfr = *(const i32x4*)(f1w + ((size_t)(b * 16384 + pbase + n * 16 + l15)) * 96 + k0);
#pragma unroll
            for (int m = 0; m < 6; m++)
                acc[m][n] = mfma16(afr[m], bfr, acc[m][n]);
        }
    }
#pragma unroll
    for (int m = 0; m < 6; m++)
#pragma unroll
        for (int n = 0; n < 4; n++)
#pragma unroll
            for (int r = 0; r < 4; r++) {
                int i2 = m * 16 + g * 4 + r;
                int pix = pbase + n * 16 + l15;
                fc[((size_t)(b * 96 + i2)) * HWSZ + pix] = f2bf(acc[m][n][r]);
            }
}

// ---- out = Fcfrout @ (F_Q - 0.5 F_V) + F_V  (bf16 MFMA, per (b,c) 128^3) ----
__global__ __launch_bounds__(256) void k_final(
        const u16* __restrict__ fc, const u16* __restrict__ gt,
        const u16* __restrict__ fvn, float* __restrict__ out) {
    int b = blockIdx.x / 96, c = blockIdx.x - b * 96;
    int lane = threadIdx.x & 63, wv_ = threadIdx.x >> 6;
    int l15 = lane & 15, g = lane >> 4;
    const u16* A = fc + ((size_t)(b * 96 + c)) * HWSZ;
    const u16* Bm = gt + ((size_t)(b * 96 + c)) * HWSZ;
    f32x4 acc[2][8];
#pragma unroll
    for (int mf = 0; mf < 2; mf++)
#pragma unroll
        for (int nf = 0; nf < 8; nf++) acc[mf][nf] = (f32x4){0.f, 0.f, 0.f, 0.f};
#pragma unroll
    for (int kc = 0; kc < 4; kc++) {
        int k0 = kc * 32 + g * 8;
        i32x4 af[2];
#pragma unroll
        for (int mf = 0; mf < 2; mf++)
            af[mf] = *(const i32x4*)(A + (size_t)(wv_ * 32 + mf * 16 + l15) * 128 + k0);
#pragma unroll
        for (int nf = 0; nf < 8; nf++) {
            i32x4 bf = *(const i32x4*)(Bm + (size_t)(nf * 16 + l15) * 128 + k0);
#pragma unroll
            for (int mf = 0; mf < 2; mf++)
                acc[mf][nf] = mfma16(af[mf], bf, acc[mf][nf]);
        }
    }
    const u16* V = fvn + ((size_t)(b * 96 + c)) * HWSZ;
    float* O = out + ((size_t)(b * 96 + c)) * HWSZ;
#pragma unroll
    for (int mf = 0; mf < 2; mf++)
#pragma unroll
        for (int nf = 0; nf < 8; nf++)
#pragma unroll
            for (int r = 0; r < 4; r++) {
                int y = wv_ * 32 + mf * 16 + g * 4 + r;
                int x = nf * 16 + l15;
                O[y * 128 + x] = acc[mf][nf][r] + bf2f(V[y * 128 + x]);
            }
}

extern "C" void kernel_launch(void* const* d_in, const int* in_sizes, int n_in,
                              void* d_out, int out_size, void* d_ws, size_t ws_size,
                              hipStream_t stream) {
    (void)in_sizes; (void)n_in;
    if (ws_size < (size_t)WS_NEED) {
        k_diag<<<2048, 256, 0, stream>>>((float*)d_out, out_size, (float)(ws_size >> 10));
        return;
    }
    const float* in1 = (const float*)d_in[0];
    const float* in2 = (const float*)d_in[1];
    const float* wq  = (const float*)d_in[2];
    const float* bq  = (const float*)d_in[3];
    const float* wk  = (const float*)d_in[4];
    const float* bk  = (const float*)d_in[5];
    const float* wv  = (const float*)d_in[6];
    const float* bv  = (const float*)d_in[7];
    const float* temp = (const float*)d_in[8];
    char* ws = (char*)d_ws;
    float* FQ   = (float*)(ws + OFF_FQ);
    float* FK   = (float*)(ws + OFF_FK);
    u16*  GT    = (u16*)(ws + OFF_GT);
    u16*  FVN   = (u16*)(ws + OFF_FVN);
    u16*  PAD1H = (u16*)(ws + OFF_PAD1H);
    u16*  PAD1L = (u16*)(ws + OFF_PAD1L);
    u16*  PAD2  = (u16*)(ws + OFF_PAD2);
    u16*  F1W   = (u16*)(ws + OFF_F1W);
    float* PART = (float*)(ws + OFF_PART);
    u16*  FCFR  = (u16*)(ws + OFF_FCFR);
    u16*  FVB   = (u16*)(ws + OFF_FVB);
    u16*  ATTNB = (u16*)(ws + OFF_ATTNB);
    u16*  WQK   = (u16*)(ws + OFF_WQK);
    u16*  WV    = (u16*)(ws + OFF_WV);

    k_zhalo<<<24, 256, 0, stream>>>(PAD1H);
    k_trans2<<<2048, 256, 0, stream>>>(in1, in2, PAD1H, PAD1L, PAD2);
    k_weights_all<<<288, 128, 0, stream>>>(wq, wk, wv, WQK, WV);
    k_convqk6<<<1024, 512, 0, stream>>>(PAD1H, PAD1L, WQK, bq, bk, FQ, FK);
    k_convv6<<<1024, 512, 0, stream>>>(PAD2, WV, bv, FVB);
    k_pattn2<<<1024, 256, 0, stream>>>(FQ, FK, F1W, PART);
    k_softmax<<<768, 128, 0, stream>>>(PART, temp, ATTNB);
    k_gprep<<<1536, 256, 0, stream>>>(FQ, FVB, GT, FVN);
    k_fcfr2<<<512, 256, 0, stream>>>(ATTNB, F1W, FCFR);
    k_final<<<768, 256, 0, stream>>>(FCFR, GT, FVN, (float*)d_out);
}

// Round 18
// 367.235 us; speedup vs baseline: 1.0907x; 1.0216x over previous
//
#include <hip/hip_runtime.h>

typedef unsigned short u16;
typedef unsigned int u32;
typedef __bf16 bf16x8 __attribute__((ext_vector_type(8)));
typedef float f32x4 __attribute__((ext_vector_type(4)));
typedef int i32x4 __attribute__((ext_vector_type(4)));

#define BATCH 8
#define CH 96
#define HWSZ 16384
#define PADP (130*130*96)   // elems per padded plane-image
#define LSTR 68             // padded LDS row stride (68*4B = 272B, 16B-aligned cols)

// ---- workspace layout (bytes) ----
#define OFF_FQ     0ULL          // f32 NHWC (convqk..gprep)
#define OFF_FK     50331648ULL   // f32 NHWC (convqk..pattn); then:
#define OFF_GT     50331648ULL   //   bf16 [B][C][x][y] (gprep..final)
#define OFF_FVN    75497472ULL   //   bf16 [B][C][y][x] (gprep..final)
#define OFF_PAD1H  100663296ULL  // bf16 padded (trans..convqk) 25958400
#define OFF_F1W    100663296ULL  //   bf16 NHWC F1tilde (pattn..fcfr2)
#define OFF_PART   126621696ULL  // f32 [B][128][96][96] 37.75MB (pattn..softmax)
#define OFF_PAD1L  126621696ULL  // bf16 padded (trans..convqk)
#define OFF_PAD2   152580096ULL  // bf16 padded (trans..convv)
#define OFF_FCFR   152580096ULL  //   bf16 [B][C][y][x] (fcfr2..final)
#define OFF_FVB    178538496ULL  // bf16 NHWC (convv..gprep)
#define OFF_ATTNB  203704320ULL  // bf16 [B][96][96]
#define OFF_WQK    203851776ULL  // bf16 packed [27][plane2][g4][co192][8]: 663552B
#define OFF_WV     204515328ULL  // bf16 packed [27][4][96][8]: 165888
#define WS_NEED    204681216ULL

__device__ __forceinline__ u16 f2bf(float f) {
    u32 u = __builtin_bit_cast(u32, f);
    u += 0x7fffu + ((u >> 16) & 1u);
    return (u16)(u >> 16);
}
__device__ __forceinline__ float bf2f(u16 h) {
    u32 u = ((u32)h) << 16;
    return __builtin_bit_cast(float, u);
}
__device__ __forceinline__ f32x4 mfma16(i32x4 a, i32x4 b, f32x4 c) {
    return __builtin_amdgcn_mfma_f32_16x16x32_bf16(
        __builtin_bit_cast(bf16x8, a), __builtin_bit_cast(bf16x8, b), c, 0, 0, 0);
}
__device__ __forceinline__ void gl_lds16(const u16* g, u16* l) {
    __builtin_amdgcn_global_load_lds(
        (const __attribute__((address_space(1))) unsigned int*)g,
        (__attribute__((address_space(3))) unsigned int*)l, 16, 0, 0);
}

__global__ __launch_bounds__(256) void k_diag(float* __restrict__ out, int n, float val) {
    for (int i = blockIdx.x * 256 + threadIdx.x; i < n; i += gridDim.x * 256) out[i] = val;
}

// ---- both inputs: NCHW f32 -> padded NHWC bf16 (in1: hi+lo, in2: hi) + halo zero ----
__global__ __launch_bounds__(256) void k_trans2(const float* __restrict__ in1,
        const float* __restrict__ in2, u16* __restrict__ p1h, u16* __restrict__ p1l,
        u16* __restrict__ p2) {
    __shared__ float tile[96][129];
    int which = blockIdx.x >> 10;
    int blk = blockIdx.x & 1023;
    const float* src = which ? in2 : in1;
    u16* dh = which ? p2 : p1h;
    u16* dl = which ? nullptr : p1l;
    int b = blk >> 7, y = blk & 127;
    const float* s = src + (size_t)b * CH * HWSZ + (size_t)y * 128;
    for (int idx = threadIdx.x; idx < CH * 128; idx += 256) {
        int c = idx >> 7, x = idx & 127;
        tile[c][x] = s[(size_t)c * HWSZ + x];
    }
    // halo zeroing (no dependence on tile; before syncthreads is fine)
    size_t obase = ((size_t)(b * 130 + y + 1) * 130 + 1) * 96;
    for (int c = threadIdx.x; c < 96; c += 256) {
        dh[obase - 96 + c] = 0;                 // x = 0 col of this row
        dh[obase + 128 * 96 + c] = 0;           // x = 129 col
        if (dl) { dl[obase - 96 + c] = 0; dl[obase + 128 * 96 + c] = 0; }
    }
    if (y == 0 || y == 127) {
        size_t rb = ((size_t)(b * 130 + (y == 0 ? 0 : 129))) * 130 * 96;
        for (int i = threadIdx.x; i < 130 * 96; i += 256) {
            dh[rb + i] = 0;
            if (dl) dl[rb + i] = 0;
        }
    }
    __syncthreads();
    for (int idx = threadIdx.x; idx < 128 * CH; idx += 256) {
        int x = idx / CH, c = idx - x * CH;
        float v = tile[c][x];
        u16 h = f2bf(v);
        dh[obase + idx] = h;
        if (dl) dl[obase + idx] = f2bf(v - bf2f(h));
    }
}

// ---- weights: QK -> [s=cic*9+tap][plane][g][co192][8] hi/lo; V -> [s][g][96][8] ----
__global__ __launch_bounds__(128) void k_weights_all(const float* __restrict__ wq,
        const float* __restrict__ wk, const float* __restrict__ wv,
        u16* __restrict__ dqk, u16* __restrict__ dv) {
    int co = blockIdx.x;  // 0..287
    if (co < 192) {
        const float* w = (co < 96) ? wq : wk;
        int cs = (co < 96) ? co : co - 96;
        for (int idx = threadIdx.x; idx < 864; idx += 128) {
            int tap = idx / 96, ci = idx - tap * 96;
            int cic = ci >> 5, g = (ci >> 3) & 3, c7 = ci & 7;
            float v = w[((size_t)cs * 96 + ci) * 9 + tap];
            u16 h = f2bf(v), lo = f2bf(v - bf2f(h));
            size_t s = (size_t)(cic * 9 + tap);
            dqk[(((s * 2 + 0) * 4 + g) * 192 + co) * 8 + c7] = h;
            dqk[(((s * 2 + 1) * 4 + g) * 192 + co) * 8 + c7] = lo;
        }
    } else {
        int cs = co - 192;
        for (int idx = threadIdx.x; idx < 864; idx += 128) {
            int tap = idx / 96, ci = idx - tap * 96;
            int cic = ci >> 5, g = (ci >> 3) & 3, c7 = ci & 7;
            float v = wv[((size_t)cs * 96 + ci) * 9 + tap];
            size_t s = (size_t)(cic * 9 + tap);
            dv[((s * 4 + g) * 96 + cs) * 8 + c7] = f2bf(v);
        }
    }
}

// ---- fused Q+K conv: round-9 champion, single full-grid launch ----
__global__ __launch_bounds__(512, 4) void k_convqk6(
        const u16* __restrict__ ph, const u16* __restrict__ pl,
        const u16* __restrict__ wqk,
        const float* __restrict__ bq, const float* __restrict__ bk,
        float* __restrict__ fq, float* __restrict__ fk) {
    __shared__ u16 wbuf[2][12288];
    const int tid = threadIdx.x;
    const int wg = ((blockIdx.x & 7) << 7) | (blockIdx.x >> 3);  // XCD swizzle: 1 image/XCD
    const int b = wg >> 7, y = wg & 127;
    const int w = tid >> 6, lane = tid & 63, l15 = lane & 15, g = lane >> 4;
    const int wx = w & 3, wc = w >> 2;
    f32x4 acc[2][6];
#pragma unroll
    for (int mf = 0; mf < 2; mf++)
#pragma unroll
        for (int f = 0; f < 6; f++) acc[mf][f] = (f32x4){0.f, 0.f, 0.f, 0.f};
    {
#pragma unroll
        for (int j = 0; j < 3; j++)
            gl_lds16(wqk + (size_t)(tid + j * 512) * 8, &wbuf[0][(size_t)(tid + j * 512) * 8]);
    }
    i32x4 ah0, ah1, al0, al1;
    {
        size_t ab = ((size_t)(b * 130 + y) * 130 + (wx * 32 + l15)) * 96 + g * 8;
        ah0 = *(const i32x4*)(ph + ab);
        ah1 = *(const i32x4*)(ph + ab + 16 * 96);
        al0 = *(const i32x4*)(pl + ab);
        al1 = *(const i32x4*)(pl + ab + 16 * 96);
    }
    __syncthreads();
    for (int s = 0; s < 27; s++) {
        const int cur = s & 1;
        i32x4 nh0, nh1, nl0, nl1;
        if (s + 1 < 27) {
            const u16* src = wqk + (size_t)(s + 1) * 12288;
#pragma unroll
            for (int j = 0; j < 3; j++)
                gl_lds16(src + (size_t)(tid + j * 512) * 8, &wbuf[cur ^ 1][(size_t)(tid + j * 512) * 8]);
            const int s1 = s + 1;
            const int cic1 = s1 / 9, tap1 = s1 - cic1 * 9;
            const int dy1 = tap1 / 3 - 1, dx1 = tap1 - (tap1 / 3) * 3 - 1;
            size_t ab = ((size_t)(b * 130 + y + 1 + dy1) * 130 + (wx * 32 + l15 + 1 + dx1)) * 96
                      + cic1 * 32 + g * 8;
            nh0 = *(const i32x4*)(ph + ab);
            nh1 = *(const i32x4*)(ph + ab + 16 * 96);
            nl0 = *(const i32x4*)(pl + ab);
            nl1 = *(const i32x4*)(pl + ab + 16 * 96);
        }
#pragma unroll
        for (int f = 0; f < 6; f++) {
            const int cob = wc * 96 + f * 16 + l15;
            i32x4 bh = *(const i32x4*)(&wbuf[cur][((0 + g) * 192 + cob) * 8]);
            i32x4 bl = *(const i32x4*)(&wbuf[cur][((4 + g) * 192 + cob) * 8]);
            acc[0][f] = mfma16(ah0, bh, acc[0][f]);
            acc[0][f] = mfma16(ah0, bl, acc[0][f]);
            acc[0][f] = mfma16(al0, bh, acc[0][f]);
            acc[1][f] = mfma16(ah1, bh, acc[1][f]);
            acc[1][f] = mfma16(ah1, bl, acc[1][f]);
            acc[1][f] = mfma16(al1, bh, acc[1][f]);
        }
        __syncthreads();
        if (s + 1 < 27) { ah0 = nh0; ah1 = nh1; al0 = nl0; al1 = nl1; }
    }
    const float* bias = wc ? bk : bq;
    float* op = wc ? fk : fq;
#pragma unroll
    for (int f = 0; f < 6; f++) {
        const int co = f * 16 + l15;
        const float bb = bias[co];
#pragma unroll
        for (int mf = 0; mf < 2; mf++) {
            const int xp = wx * 32 + mf * 16 + g * 4;
#pragma unroll
            for (int r = 0; r < 4; r++)
                op[((size_t)((b * 128 + y) * 128 + xp + r)) * 96 + co] = acc[mf][f][r] + bb;
        }
    }
}

// ---- V conv v7: 3-step LDS groups -> 9 barriers instead of 27 ----
__global__ __launch_bounds__(512, 4) void k_convv7(
        const u16* __restrict__ p2, const u16* __restrict__ wv,
        const float* __restrict__ bv, u16* __restrict__ fvb) {
    __shared__ u16 vbuf[2][9216];   // 3 steps x 3072 u16 per buffer (18KB each)
    const int tid = threadIdx.x;
    const int wg = ((blockIdx.x & 7) << 7) | (blockIdx.x >> 3);
    const int b = wg >> 7, y = wg & 127;
    const int w = tid >> 6, lane = tid & 63, l15 = lane & 15, g = lane >> 4;
    const int wx = w & 3, wc = w >> 2;
    f32x4 acc[2][3];
#pragma unroll
    for (int mf = 0; mf < 2; mf++)
#pragma unroll
        for (int f = 0; f < 3; f++) acc[mf][f] = (f32x4){0.f, 0.f, 0.f, 0.f};
    {   // stage group 0: 1152 chunks of 16B
        gl_lds16(wv + (size_t)tid * 8, &vbuf[0][(size_t)tid * 8]);
        gl_lds16(wv + (size_t)(512 + tid) * 8, &vbuf[0][(size_t)(512 + tid) * 8]);
        if (tid < 128)
            gl_lds16(wv + (size_t)(1024 + tid) * 8, &vbuf[0][(size_t)(1024 + tid) * 8]);
    }
    i32x4 ah0, ah1;
    {   // A prefetch for step 0 (cic=0, tap=0: dy=-1, dx=-1)
        size_t ab = ((size_t)(b * 130 + y) * 130 + (wx * 32 + l15)) * 96 + g * 8;
        ah0 = *(const i32x4*)(p2 + ab);
        ah1 = *(const i32x4*)(p2 + ab + 16 * 96);
    }
    __syncthreads();
    for (int gp = 0; gp < 9; gp++) {
        const int cur = gp & 1;
        if (gp + 1 < 9) {   // stage next 3-step group into other buffer
            const u16* src = wv + (size_t)(gp + 1) * 9216;
            gl_lds16(src + (size_t)tid * 8, &vbuf[cur ^ 1][(size_t)tid * 8]);
            gl_lds16(src + (size_t)(512 + tid) * 8, &vbuf[cur ^ 1][(size_t)(512 + tid) * 8]);
            if (tid < 128)
                gl_lds16(src + (size_t)(1024 + tid) * 8, &vbuf[cur ^ 1][(size_t)(1024 + tid) * 8]);
        }
#pragma unroll
        for (int t = 0; t < 3; t++) {
            const int s = gp * 3 + t;
            i32x4 nh0, nh1;
            if (s + 1 < 27) {   // rolling A prefetch (no barrier between steps)
                const int s1 = s + 1;
                const int cic1 = s1 / 9, tap1 = s1 - cic1 * 9;
                const int dy1 = tap1 / 3 - 1, dx1 = tap1 - (tap1 / 3) * 3 - 1;
                size_t ab = ((size_t)(b * 130 + y + 1 + dy1) * 130 + (wx * 32 + l15 + 1 + dx1)) * 96
                          + cic1 * 32 + g * 8;
                nh0 = *(const i32x4*)(p2 + ab);
                nh1 = *(const i32x4*)(p2 + ab + 16 * 96);
            }
#pragma unroll
            for (int f = 0; f < 3; f++) {
                const int cof = wc * 48 + f * 16 + l15;
                i32x4 bfr = *(const i32x4*)(&vbuf[cur][(size_t)t * 3072 + (g * 96 + cof) * 8]);
                acc[0][f] = mfma16(ah0, bfr, acc[0][f]);
                acc[1][f] = mfma16(ah1, bfr, acc[1][f]);
            }
            if (s + 1 < 27) { ah0 = nh0; ah1 = nh1; }
        }
        __syncthreads();   // one barrier per 3-step group
    }
#pragma unroll
    for (int f = 0; f < 3; f++) {
        const int co = wc * 48 + f * 16 + l15;
        const float bb = bv[co];
#pragma unroll
        for (int mf = 0; mf < 2; mf++) {
            const int xp = wx * 32 + mf * 16 + g * 4;
#pragma unroll
            for (int r = 0; r < 4; r++)
                fvb[((size_t)((b * 128 + y) * 128 + xp + r)) * 96 + co] = f2bf(acc[mf][f][r] + bb);
        }
    }
}

// ---- FUSED patch+attn: 1024 blocks, 2x 64-px chunks, vectorized LDS access ----
__global__ __launch_bounds__(256) void k_pattn2(
        const float* __restrict__ fq, const float* __restrict__ fk,
        u16* __restrict__ f1w, float* __restrict__ part) {
    __shared__ __attribute__((aligned(16))) float qs[96 * LSTR];
    __shared__ __attribute__((aligned(16))) float ks[96 * LSTR];
    int wg = ((blockIdx.x & 7) << 7) | (blockIdx.x >> 3);   // XCD swizzle
    int b = wg >> 7, ys = (wg >> 2) & 31, xq = wg & 3;
    int y0 = ys * 4, x0 = xq * 32;
    int tx = threadIdx.x & 15, ty = threadIdx.x >> 4;
    double accD[6][6];
#pragma unroll
    for (int a = 0; a < 6; a++)
#pragma unroll
        for (int bb = 0; bb < 6; bb++) accD[a][bb] = 0.0;
#pragma unroll
    for (int cx = 0; cx < 2; cx++) {
        for (int idx = threadIdx.x; idx < 1536; idx += 256) {
            int p = idx / 24, c0 = (idx - p * 24) * 4;
            int ry = p >> 4, rx = p & 15;
            size_t off = ((size_t)((b * 128 + y0 + ry) * 128 + x0 + cx * 16 + rx)) * 96 + c0;
            f32x4 qv = *(const f32x4*)(fq + off);
            f32x4 kv = *(const f32x4*)(fk + off);
#pragma unroll
            for (int u = 0; u < 4; u++) {
                qs[(c0 + u) * LSTR + p] = qv[u];
                ks[(c0 + u) * LSTR + p] = kv[u];
            }
        }
        __syncthreads();
        for (int item = threadIdx.x; item < 384; item += 256) {
            int j = item / 96, c = item - j * 96;
            f32x4 A[4], Bm[4];
#pragma unroll
            for (int r = 0; r < 4; r++) {
                A[r]  = *(const f32x4*)&qs[c * LSTR + r * 16 + j * 4];
                Bm[r] = *(const f32x4*)&ks[c * LSTR + r * 16 + j * 4];
            }
            float rsB[4], csB[4], rsA[4], tot = 0.f;
#pragma unroll
            for (int r = 0; r < 4; r++) {
                rsB[r] = Bm[r][0] + Bm[r][1] + Bm[r][2] + Bm[r][3];
                rsA[r] = A[r][0] + A[r][1] + A[r][2] + A[r][3];
                tot += rsB[r];
            }
#pragma unroll
            for (int m = 0; m < 4; m++) csB[m] = Bm[0][m] + Bm[1][m] + Bm[2][m] + Bm[3][m];
#pragma unroll
            for (int r = 0; r < 4; r++) {
#pragma unroll
                for (int m = 0; m < 4; m++) {
                    float ab = A[r][0] * Bm[0][m] + A[r][1] * Bm[1][m]
                             + A[r][2] * Bm[2][m] + A[r][3] * Bm[3][m];
                    f1w[((size_t)((b * 128 + y0 + r) * 128 + x0 + cx * 16 + j * 4 + m)) * 96 + c]
                        = f2bf(8.f * ab + 2.f * rsA[r] * csB[m]);
                }
                f32x4 kt;
#pragma unroll
                for (int m = 0; m < 4; m++)
                    kt[m] = 64.f * Bm[r][m] + 16.f * (rsB[r] + csB[m]) + 4.f * tot;
                *(f32x4*)&ks[c * LSTR + r * 16 + j * 4] = kt;
            }
        }
        __syncthreads();
        float acc[6][6];
#pragma unroll
        for (int a = 0; a < 6; a++)
#pragma unroll
            for (int bb = 0; bb < 6; bb++) acc[a][bb] = 0.f;
        for (int l4 = 0; l4 < 16; l4++) {
            f32x4 qv4[6], kv4[6];
#pragma unroll
            for (int a = 0; a < 6; a++)
                qv4[a] = *(const f32x4*)&qs[(ty + 16 * a) * LSTR + l4 * 4];
#pragma unroll
            for (int bb = 0; bb < 6; bb++)
                kv4[bb] = *(const f32x4*)&ks[(tx + 16 * bb) * LSTR + l4 * 4];
#pragma unroll
            for (int a = 0; a < 6; a++)
#pragma unroll
                for (int bb = 0; bb < 6; bb++) {
                    acc[a][bb] += qv4[a][0] * kv4[bb][0];
                    acc[a][bb] += qv4[a][1] * kv4[bb][1];
                    acc[a][bb] += qv4[a][2] * kv4[bb][2];
                    acc[a][bb] += qv4[a][3] * kv4[bb][3];
                }
        }
#pragma unroll
        for (int a = 0; a < 6; a++)
#pragma unroll
            for (int bb = 0; bb < 6; bb++) accD[a][bb] += (double)acc[a][bb];
        __syncthreads();
    }
    int s128 = ys * 4 + xq;
#pragma unroll
    for (int a = 0; a < 6; a++)
#pragma unroll
        for (int bb = 0; bb < 6; bb++)
            part[((size_t)((b * 128 + s128) * 96 + ty + 16 * a)) * 96 + tx + 16 * bb]
                = (float)accD[a][bb];
}

// ---- reduce 128 slices (f64) + temperature + row softmax -> bf16 weights ----
__global__ __launch_bounds__(128) void k_softmax(
        const float* __restrict__ part, const float* __restrict__ temp,
        u16* __restrict__ attnb) {
    __shared__ float red[128];
    int b = blockIdx.x / 96, i2 = blockIdx.x - b * 96;
    int j2 = threadIdx.x;
    float v = 0.f;
    if (j2 < 96) {
        double vd = 0.0;
        for (int s = 0; s < 128; s++)
            vd += (double)part[((size_t)((b * 128 + s) * 96 + i2)) * 96 + j2];
        v = (float)vd * temp[0];
    }
    red[j2] = (j2 < 96) ? v : -3.4e38f;
    __syncthreads();
    for (int off = 64; off >= 1; off >>= 1) {
        if (j2 < off) red[j2] = fmaxf(red[j2], red[j2 + off]);
        __syncthreads();
    }
    float mx = red[0];
    __syncthreads();
    float e = (j2 < 96) ? expf(v - mx) : 0.f;
    red[j2] = e;
    __syncthreads();
    for (int off = 64; off >= 1; off >>= 1) {
        if (j2 < off) red[j2] += red[j2 + off];
        __syncthreads();
    }
    float sum = red[0];
    if (j2 < 96) attnb[((size_t)(b * 96) + i2) * 96 + j2] = f2bf(e / sum);
}

// ---- Gt = (F_Q - 0.5 F_V)^T, Fvn = F_V, both bf16 [B][C][.][.] ----
__global__ __launch_bounds__(256) void k_gprep(
        const float* __restrict__ fqn, const u16* __restrict__ fvb,
        u16* __restrict__ gt, u16* __restrict__ fvn) {
    __shared__ u16 lg[8 * 32 * 33];
    __shared__ u16 lv[8 * 32 * 33];
    int blk = blockIdx.x;
    int b = blk / 192;
    int r = blk - b * 192;
    int yt = r / 48; r -= yt * 48;
    int xt = r / 12; int cc = r - xt * 12;
    int y0 = yt * 32, x0 = xt * 32, c0 = cc * 8;
    for (int idx = threadIdx.x; idx < 8192; idx += 256) {
        int pix = idx >> 3, cl = idx & 7;
        int yy = pix >> 5, xx = pix & 31;
        size_t off = ((size_t)((b * 128 + y0 + yy) * 128 + x0 + xx)) * 96 + c0 + cl;
        float q = fqn[off];
        float v = bf2f(fvb[off]);
        int la = (cl * 32 + yy) * 33 + xx;
        lg[la] = f2bf(q - 0.5f * v);
        lv[la] = f2bf(v);
    }
    __syncthreads();
    for (int idx = threadIdx.x; idx < 8192; idx += 256) {
        int yy = idx & 31, xl = (idx >> 5) & 31, cl = idx >> 10;
        gt[((size_t)((b * 96 + c0 + cl) * 128 + x0 + xl)) * 128 + y0 + yy] = lg[(cl * 32 + yy) * 33 + xl];
    }
    for (int idx = threadIdx.x; idx < 8192; idx += 256) {
        int xx = idx & 31, yl = (idx >> 5) & 31, cl = idx >> 10;
        fvn[((size_t)((b * 96 + c0 + cl) * 128 + y0 + yl)) * 128 + x0 + xx] = lv[(cl * 32 + yl) * 33 + xx];
    }
}

// ---- FCFR[b][i][pix] = sum_j attn[i][j] * F1W[b][pix][j]  (bf16 MFMA) ----
__global__ __launch_bounds__(256) void k_fcfr2(
        const u16* __restrict__ attnb, const u16* __restrict__ f1w,
        u16* __restrict__ fc) {
    int b = blockIdx.x >> 6, pc = blockIdx.x & 63;
    int lane = threadIdx.x & 63, wv_ = threadIdx.x >> 6;
    int l15 = lane & 15, g = lane >> 4;
    int pbase = pc * 256 + wv_ * 64;
    f32x4 acc[6][4];
#pragma unroll
    for (int m = 0; m < 6; m++)
#pragma unroll
        for (int n = 0; n < 4; n++) acc[m][n] = (f32x4){0.f, 0.f, 0.f, 0.f};
#pragma unroll
    for (int ks = 0; ks < 3; ks++) {
        int k0 = ks * 32 + g * 8;
        i32x4 afr[6];
#pragma unroll
        for (int m = 0; m < 6; m++)
            afr[m] = *(const i32x4*)(attnb + ((size_t)(b * 96 + m * 16 + l15)) * 96 + k0);
#pragma unroll
        for (int n = 0; n < 4; n++) {
            i32x4 bfr = *(const i32x4*)(f1w + ((size_t)(b * 16384 + pbase + n * 16 + l15)) * 96 + k0);
#pragma unroll
            for (int m = 0; m < 6; m++)
                acc[m][n] = mfma16(afr[m], bfr, acc[m][n]);
        }
    }
#pragma unroll
    for (int m = 0; m < 6; m++)
#pragma unroll
        for (int n = 0; n < 4; n++)
#pragma unroll
            for (int r = 0; r < 4; r++) {
                int i2 = m * 16 + g * 4 + r;
                int pix = pbase + n * 16 + l15;
                fc[((size_t)(b * 96 + i2)) * HWSZ + pix] = f2bf(acc[m][n][r]);
            }
}

// ---- out = Fcfrout @ (F_Q - 0.5 F_V) + F_V  (bf16 MFMA, per (b,c) 128^3) ----
__global__ __launch_bounds__(256) void k_final(
        const u16* __restrict__ fc, const u16* __restrict__ gt,
        const u16* __restrict__ fvn, float* __restrict__ out) {
    int b = blockIdx.x / 96, c = blockIdx.x - b * 96;
    int lane = threadIdx.x & 63, wv_ = threadIdx.x >> 6;
    int l15 = lane & 15, g = lane >> 4;
    const u16* A = fc + ((size_t)(b * 96 + c)) * HWSZ;
    const u16* Bm = gt + ((size_t)(b * 96 + c)) * HWSZ;
    f32x4 acc[2][8];
#pragma unroll
    for (int mf = 0; mf < 2; mf++)
#pragma unroll
        for (int nf = 0; nf < 8; nf++) acc[mf][nf] = (f32x4){0.f, 0.f, 0.f, 0.f};
#pragma unroll
    for (int kc = 0; kc < 4; kc++) {
        int k0 = kc * 32 + g * 8;
        i32x4 af[2];
#pragma unroll
        for (int mf = 0; mf < 2; mf++)
            af[mf] = *(const i32x4*)(A + (size_t)(wv_ * 32 + mf * 16 + l15) * 128 + k0);
#pragma unroll
        for (int nf = 0; nf < 8; nf++) {
            i32x4 bf = *(const i32x4*)(Bm + (size_t)(nf * 16 + l15) * 128 + k0);
#pragma unroll
            for (int mf = 0; mf < 2; mf++)
                acc[mf][nf] = mfma16(af[mf], bf, acc[mf][nf]);
        }
    }
    const u16* V = fvn + ((size_t)(b * 96 + c)) * HWSZ;
    float* O = out + ((size_t)(b * 96 + c)) * HWSZ;
#pragma unroll
    for (int mf = 0; mf < 2; mf++)
#pragma unroll
        for (int nf = 0; nf < 8; nf++)
#pragma unroll
            for (int r = 0; r < 4; r++) {
                int y = wv_ * 32 + mf * 16 + g * 4 + r;
                int x = nf * 16 + l15;
                O[y * 128 + x] = acc[mf][nf][r] + bf2f(V[y * 128 + x]);
            }
}

extern "C" void kernel_launch(void* const* d_in, const int* in_sizes, int n_in,
                              void* d_out, int out_size, void* d_ws, size_t ws_size,
                              hipStream_t stream) {
    (void)in_sizes; (void)n_in;
    if (ws_size < (size_t)WS_NEED) {
        k_diag<<<2048, 256, 0, stream>>>((float*)d_out, out_size, (float)(ws_size >> 10));
        return;
    }
    const float* in1 = (const float*)d_in[0];
    const float* in2 = (const float*)d_in[1];
    const float* wq  = (const float*)d_in[2];
    const float* bq  = (const float*)d_in[3];
    const float* wk  = (const float*)d_in[4];
    const float* bk  = (const float*)d_in[5];
    const float* wv  = (const float*)d_in[6];
    const float* bv  = (const float*)d_in[7];
    const float* temp = (const float*)d_in[8];
    char* ws = (char*)d_ws;
    float* FQ   = (float*)(ws + OFF_FQ);
    float* FK   = (float*)(ws + OFF_FK);
    u16*  GT    = (u16*)(ws + OFF_GT);
    u16*  FVN   = (u16*)(ws + OFF_FVN);
    u16*  PAD1H = (u16*)(ws + OFF_PAD1H);
    u16*  PAD1L = (u16*)(ws + OFF_PAD1L);
    u16*  PAD2  = (u16*)(ws + OFF_PAD2);
    u16*  F1W   = (u16*)(ws + OFF_F1W);
    float* PART = (float*)(ws + OFF_PART);
    u16*  FCFR  = (u16*)(ws + OFF_FCFR);
    u16*  FVB   = (u16*)(ws + OFF_FVB);
    u16*  ATTNB = (u16*)(ws + OFF_ATTNB);
    u16*  WQK   = (u16*)(ws + OFF_WQK);
    u16*  WV    = (u16*)(ws + OFF_WV);

    k_trans2<<<2048, 256, 0, stream>>>(in1, in2, PAD1H, PAD1L, PAD2);
    k_weights_all<<<288, 128, 0, stream>>>(wq, wk, wv, WQK, WV);
    k_convqk6<<<1024, 512, 0, stream>>>(PAD1H, PAD1L, WQK, bq, bk, FQ, FK);
    k_convv7<<<1024, 512, 0, stream>>>(PAD2, WV, bv, FVB);
    k_pattn2<<<1024, 256, 0, stream>>>(FQ, FK, F1W, PART);
    k_softmax<<<768, 128, 0, stream>>>(PART, temp, ATTNB);
    k_gprep<<<1536, 256, 0, stream>>>(FQ, FVB, GT, FVN);
    k_fcfr2<<<512, 256, 0, stream>>>(ATTNB, F1W, FCFR);
    k_final<<<768, 256, 0, stream>>>(FCFR, GT, FVN, (float*)d_out);
}

// Round 19
// 339.837 us; speedup vs baseline: 1.1787x; 1.0806x over previous
//
#include <hip/hip_runtime.h>

typedef unsigned short u16;
typedef unsigned int u32;
typedef __bf16 bf16x8 __attribute__((ext_vector_type(8)));
typedef float f32x4 __attribute__((ext_vector_type(4)));
typedef int i32x4 __attribute__((ext_vector_type(4)));
typedef unsigned int u32x2 __attribute__((ext_vector_type(2)));

#define BATCH 8
#define CH 96
#define HWSZ 16384
#define PADP (130*130*96)   // elems per padded plane-image
#define LSTR 68             // padded LDS row stride (68*4B = 272B, 16B-aligned cols)

// ---- workspace layout (bytes) ----
#define OFF_FQ     0ULL          // f32 PLANAR [B][C][y][x] (convqk..gprep2)
#define OFF_FK     50331648ULL   // f32 PLANAR (convqk..pattn); then:
#define OFF_GT     50331648ULL   //   bf16 [B][C][x][y] (gprep2..final)
#define OFF_PAD1H  100663296ULL  // bf16 padded (trans..convqk) 25958400
#define OFF_F1W    100663296ULL  //   bf16 NHWC F1tilde (pattn..fcfr2)
#define OFF_PART   126621696ULL  // f32 [B][128][96][96] 37.75MB (pattn..softmax)
#define OFF_PAD1L  126621696ULL  // bf16 padded (trans..convqk)
#define OFF_PAD2   152580096ULL  // bf16 padded (trans..convv)
#define OFF_FCFR   152580096ULL  //   bf16 [B][C][y][x] (fcfr2..final)
#define OFF_FVN    178538496ULL  // bf16 PLANAR [B][C][y][x] (convv..final)
#define OFF_ATTNB  203704320ULL  // bf16 [B][96][96]
#define OFF_WQK    203851776ULL  // bf16 packed [27][plane2][g4][co192][8]: 663552B
#define OFF_WV     204515328ULL  // bf16 packed [27][4][96][8]: 165888
#define WS_NEED    204681216ULL

__device__ __forceinline__ u16 f2bf(float f) {
    u32 u = __builtin_bit_cast(u32, f);
    u += 0x7fffu + ((u >> 16) & 1u);
    return (u16)(u >> 16);
}
__device__ __forceinline__ float bf2f(u16 h) {
    u32 u = ((u32)h) << 16;
    return __builtin_bit_cast(float, u);
}
__device__ __forceinline__ f32x4 mfma16(i32x4 a, i32x4 b, f32x4 c) {
    return __builtin_amdgcn_mfma_f32_16x16x32_bf16(
        __builtin_bit_cast(bf16x8, a), __builtin_bit_cast(bf16x8, b), c, 0, 0, 0);
}
__device__ __forceinline__ void gl_lds16(const u16* g, u16* l) {
    __builtin_amdgcn_global_load_lds(
        (const __attribute__((address_space(1))) unsigned int*)g,
        (__attribute__((address_space(3))) unsigned int*)l, 16, 0, 0);
}

__global__ __launch_bounds__(256) void k_diag(float* __restrict__ out, int n, float val) {
    for (int i = blockIdx.x * 256 + threadIdx.x; i < n; i += gridDim.x * 256) out[i] = val;
}

// ---- both inputs: NCHW f32 -> padded NHWC bf16 (in1: hi+lo, in2: hi) + halo zero ----
__global__ __launch_bounds__(256) void k_trans2(const float* __restrict__ in1,
        const float* __restrict__ in2, u16* __restrict__ p1h, u16* __restrict__ p1l,
        u16* __restrict__ p2) {
    __shared__ float tile[96][129];
    int which = blockIdx.x >> 10;
    int blk = blockIdx.x & 1023;
    const float* src = which ? in2 : in1;
    u16* dh = which ? p2 : p1h;
    u16* dl = which ? nullptr : p1l;
    int b = blk >> 7, y = blk & 127;
    const float* s = src + (size_t)b * CH * HWSZ + (size_t)y * 128;
    for (int idx = threadIdx.x; idx < CH * 128; idx += 256) {
        int c = idx >> 7, x = idx & 127;
        tile[c][x] = s[(size_t)c * HWSZ + x];
    }
    size_t obase = ((size_t)(b * 130 + y + 1) * 130 + 1) * 96;
    for (int c = threadIdx.x; c < 96; c += 256) {
        dh[obase - 96 + c] = 0;
        dh[obase + 128 * 96 + c] = 0;
        if (dl) { dl[obase - 96 + c] = 0; dl[obase + 128 * 96 + c] = 0; }
    }
    if (y == 0 || y == 127) {
        size_t rb = ((size_t)(b * 130 + (y == 0 ? 0 : 129))) * 130 * 96;
        for (int i = threadIdx.x; i < 130 * 96; i += 256) {
            dh[rb + i] = 0;
            if (dl) dl[rb + i] = 0;
        }
    }
    __syncthreads();
    for (int idx = threadIdx.x; idx < 128 * CH; idx += 256) {
        int x = idx / CH, c = idx - x * CH;
        float v = tile[c][x];
        u16 h = f2bf(v);
        dh[obase + idx] = h;
        if (dl) dl[obase + idx] = f2bf(v - bf2f(h));
    }
}

// ---- weights: QK -> [s=cic*9+tap][plane][g][co192][8] hi/lo; V -> [s][g][96][8] ----
__global__ __launch_bounds__(128) void k_weights_all(const float* __restrict__ wq,
        const float* __restrict__ wk, const float* __restrict__ wv,
        u16* __restrict__ dqk, u16* __restrict__ dv) {
    int co = blockIdx.x;  // 0..287
    if (co < 192) {
        const float* w = (co < 96) ? wq : wk;
        int cs = (co < 96) ? co : co - 96;
        for (int idx = threadIdx.x; idx < 864; idx += 128) {
            int tap = idx / 96, ci = idx - tap * 96;
            int cic = ci >> 5, g = (ci >> 3) & 3, c7 = ci & 7;
            float v = w[((size_t)cs * 96 + ci) * 9 + tap];
            u16 h = f2bf(v), lo = f2bf(v - bf2f(h));
            size_t s = (size_t)(cic * 9 + tap);
            dqk[(((s * 2 + 0) * 4 + g) * 192 + co) * 8 + c7] = h;
            dqk[(((s * 2 + 1) * 4 + g) * 192 + co) * 8 + c7] = lo;
        }
    } else {
        int cs = co - 192;
        for (int idx = threadIdx.x; idx < 864; idx += 128) {
            int tap = idx / 96, ci = idx - tap * 96;
            int cic = ci >> 5, g = (ci >> 3) & 3, c7 = ci & 7;
            float v = wv[((size_t)cs * 96 + ci) * 9 + tap];
            size_t s = (size_t)(cic * 9 + tap);
            dv[((s * 4 + g) * 96 + cs) * 8 + c7] = f2bf(v);
        }
    }
}

// ---- fused Q+K conv: round-9 champion + PLANAR f32x4 epilogue ----
__global__ __launch_bounds__(512, 4) void k_convqk6p(
        const u16* __restrict__ ph, const u16* __restrict__ pl,
        const u16* __restrict__ wqk,
        const float* __restrict__ bq, const float* __restrict__ bk,
        float* __restrict__ fq, float* __restrict__ fk) {
    __shared__ u16 wbuf[2][12288];
    const int tid = threadIdx.x;
    const int wg = ((blockIdx.x & 7) << 7) | (blockIdx.x >> 3);  // XCD swizzle: 1 image/XCD
    const int b = wg >> 7, y = wg & 127;
    const int w = tid >> 6, lane = tid & 63, l15 = lane & 15, g = lane >> 4;
    const int wx = w & 3, wc = w >> 2;
    f32x4 acc[2][6];
#pragma unroll
    for (int mf = 0; mf < 2; mf++)
#pragma unroll
        for (int f = 0; f < 6; f++) acc[mf][f] = (f32x4){0.f, 0.f, 0.f, 0.f};
    {
#pragma unroll
        for (int j = 0; j < 3; j++)
            gl_lds16(wqk + (size_t)(tid + j * 512) * 8, &wbuf[0][(size_t)(tid + j * 512) * 8]);
    }
    i32x4 ah0, ah1, al0, al1;
    {
        size_t ab = ((size_t)(b * 130 + y) * 130 + (wx * 32 + l15)) * 96 + g * 8;
        ah0 = *(const i32x4*)(ph + ab);
        ah1 = *(const i32x4*)(ph + ab + 16 * 96);
        al0 = *(const i32x4*)(pl + ab);
        al1 = *(const i32x4*)(pl + ab + 16 * 96);
    }
    __syncthreads();
    for (int s = 0; s < 27; s++) {
        const int cur = s & 1;
        i32x4 nh0, nh1, nl0, nl1;
        if (s + 1 < 27) {
            const u16* src = wqk + (size_t)(s + 1) * 12288;
#pragma unroll
            for (int j = 0; j < 3; j++)
                gl_lds16(src + (size_t)(tid + j * 512) * 8, &wbuf[cur ^ 1][(size_t)(tid + j * 512) * 8]);
            const int s1 = s + 1;
            const int cic1 = s1 / 9, tap1 = s1 - cic1 * 9;
            const int dy1 = tap1 / 3 - 1, dx1 = tap1 - (tap1 / 3) * 3 - 1;
            size_t ab = ((size_t)(b * 130 + y + 1 + dy1) * 130 + (wx * 32 + l15 + 1 + dx1)) * 96
                      + cic1 * 32 + g * 8;
            nh0 = *(const i32x4*)(ph + ab);
            nh1 = *(const i32x4*)(ph + ab + 16 * 96);
            nl0 = *(const i32x4*)(pl + ab);
            nl1 = *(const i32x4*)(pl + ab + 16 * 96);
        }
#pragma unroll
        for (int f = 0; f < 6; f++) {
            const int cob = wc * 96 + f * 16 + l15;
            i32x4 bh = *(const i32x4*)(&wbuf[cur][((0 + g) * 192 + cob) * 8]);
            i32x4 bl = *(const i32x4*)(&wbuf[cur][((4 + g) * 192 + cob) * 8]);
            acc[0][f] = mfma16(ah0, bh, acc[0][f]);
            acc[0][f] = mfma16(ah0, bl, acc[0][f]);
            acc[0][f] = mfma16(al0, bh, acc[0][f]);
            acc[1][f] = mfma16(ah1, bh, acc[1][f]);
            acc[1][f] = mfma16(ah1, bl, acc[1][f]);
            acc[1][f] = mfma16(al1, bh, acc[1][f]);
        }
        __syncthreads();
        if (s + 1 < 27) { ah0 = nh0; ah1 = nh1; al0 = nl0; al1 = nl1; }
    }
    const float* bias = wc ? bk : bq;
    float* op = wc ? fk : fq;
#pragma unroll
    for (int f = 0; f < 6; f++) {
        const int co = f * 16 + l15;
        const float bb = bias[co];
#pragma unroll
        for (int mf = 0; mf < 2; mf++) {
            const int xp = wx * 32 + mf * 16 + g * 4;
            f32x4 o;
#pragma unroll
            for (int r = 0; r < 4; r++) o[r] = acc[mf][f][r] + bb;
            *(f32x4*)(op + ((size_t)((b * 96 + co) * 128 + y)) * 128 + xp) = o;
        }
    }
}

// ---- V conv v7: 3-step LDS groups, PLANAR bf16 epilogue (8B stores) ----
__global__ __launch_bounds__(512, 4) void k_convv7p(
        const u16* __restrict__ p2, const u16* __restrict__ wv,
        const float* __restrict__ bv, u16* __restrict__ fvn) {
    __shared__ u16 vbuf[2][9216];   // 3 steps x 3072 u16 per buffer
    const int tid = threadIdx.x;
    const int wg = ((blockIdx.x & 7) << 7) | (blockIdx.x >> 3);
    const int b = wg >> 7, y = wg & 127;
    const int w = tid >> 6, lane = tid & 63, l15 = lane & 15, g = lane >> 4;
    const int wx = w & 3, wc = w >> 2;
    f32x4 acc[2][3];
#pragma unroll
    for (int mf = 0; mf < 2; mf++)
#pragma unroll
        for (int f = 0; f < 3; f++) acc[mf][f] = (f32x4){0.f, 0.f, 0.f, 0.f};
    {
        gl_lds16(wv + (size_t)tid * 8, &vbuf[0][(size_t)tid * 8]);
        gl_lds16(wv + (size_t)(512 + tid) * 8, &vbuf[0][(size_t)(512 + tid) * 8]);
        if (tid < 128)
            gl_lds16(wv + (size_t)(1024 + tid) * 8, &vbuf[0][(size_t)(1024 + tid) * 8]);
    }
    i32x4 ah0, ah1;
    {
        size_t ab = ((size_t)(b * 130 + y) * 130 + (wx * 32 + l15)) * 96 + g * 8;
        ah0 = *(const i32x4*)(p2 + ab);
        ah1 = *(const i32x4*)(p2 + ab + 16 * 96);
    }
    __syncthreads();
    for (int gp = 0; gp < 9; gp++) {
        const int cur = gp & 1;
        if (gp + 1 < 9) {
            const u16* src = wv + (size_t)(gp + 1) * 9216;
            gl_lds16(src + (size_t)tid * 8, &vbuf[cur ^ 1][(size_t)tid * 8]);
            gl_lds16(src + (size_t)(512 + tid) * 8, &vbuf[cur ^ 1][(size_t)(512 + tid) * 8]);
            if (tid < 128)
                gl_lds16(src + (size_t)(1024 + tid) * 8, &vbuf[cur ^ 1][(size_t)(1024 + tid) * 8]);
        }
#pragma unroll
        for (int t = 0; t < 3; t++) {
            const int s = gp * 3 + t;
            i32x4 nh0, nh1;
            if (s + 1 < 27) {
                const int s1 = s + 1;
                const int cic1 = s1 / 9, tap1 = s1 - cic1 * 9;
                const int dy1 = tap1 / 3 - 1, dx1 = tap1 - (tap1 / 3) * 3 - 1;
                size_t ab = ((size_t)(b * 130 + y + 1 + dy1) * 130 + (wx * 32 + l15 + 1 + dx1)) * 96
                          + cic1 * 32 + g * 8;
                nh0 = *(const i32x4*)(p2 + ab);
                nh1 = *(const i32x4*)(p2 + ab + 16 * 96);
            }
#pragma unroll
            for (int f = 0; f < 3; f++) {
                const int cof = wc * 48 + f * 16 + l15;
                i32x4 bfr = *(const i32x4*)(&vbuf[cur][(size_t)t * 3072 + (g * 96 + cof) * 8]);
                acc[0][f] = mfma16(ah0, bfr, acc[0][f]);
                acc[1][f] = mfma16(ah1, bfr, acc[1][f]);
            }
            if (s + 1 < 27) { ah0 = nh0; ah1 = nh1; }
        }
        __syncthreads();
    }
#pragma unroll
    for (int f = 0; f < 3; f++) {
        const int co = wc * 48 + f * 16 + l15;
        const float bb = bv[co];
#pragma unroll
        for (int mf = 0; mf < 2; mf++) {
            const int xp = wx * 32 + mf * 16 + g * 4;
            u32 lo = (u32)f2bf(acc[mf][f][0]) | ((u32)f2bf(acc[mf][f][1] + bb - bb + bb) << 16);
            // build carefully: each element + bias
            u16 o0 = f2bf(acc[mf][f][0] + bb), o1 = f2bf(acc[mf][f][1] + bb);
            u16 o2 = f2bf(acc[mf][f][2] + bb), o3 = f2bf(acc[mf][f][3] + bb);
            u32x2 pk;
            pk[0] = (u32)o0 | ((u32)o1 << 16);
            pk[1] = (u32)o2 | ((u32)o3 << 16);
            (void)lo;
            *(u32x2*)(fvn + ((size_t)((b * 96 + co) * 128 + y)) * 128 + xp) = pk;
        }
    }
}

// ---- FUSED patch+attn: planar inputs, fully vectorized staging ----
__global__ __launch_bounds__(256) void k_pattn2p(
        const float* __restrict__ fq, const float* __restrict__ fk,
        u16* __restrict__ f1w, float* __restrict__ part) {
    __shared__ __attribute__((aligned(16))) float qs[96 * LSTR];
    __shared__ __attribute__((aligned(16))) float ks[96 * LSTR];
    int wg = ((blockIdx.x & 7) << 7) | (blockIdx.x >> 3);   // XCD swizzle
    int b = wg >> 7, ys = (wg >> 2) & 31, xq = wg & 3;
    int y0 = ys * 4, x0 = xq * 32;
    int tx = threadIdx.x & 15, ty = threadIdx.x >> 4;
    double accD[6][6];
#pragma unroll
    for (int a = 0; a < 6; a++)
#pragma unroll
        for (int bb = 0; bb < 6; bb++) accD[a][bb] = 0.0;
#pragma unroll
    for (int cx = 0; cx < 2; cx++) {
        // stage 64 px x 96 c from PLANAR: f32x4 loads + f32x4 LDS writes
        for (int idx = threadIdx.x; idx < 1536; idx += 256) {
            int c = idx >> 4, rem = idx & 15, ry = rem >> 2, q4 = rem & 3;
            size_t off = ((size_t)((b * 96 + c) * 128 + y0 + ry)) * 128 + x0 + cx * 16 + q4 * 4;
            f32x4 qv = *(const f32x4*)(fq + off);
            f32x4 kv = *(const f32x4*)(fk + off);
            int p0 = ry * 16 + q4 * 4;
            *(f32x4*)&qs[c * LSTR + p0] = qv;
            *(f32x4*)&ks[c * LSTR + p0] = kv;
        }
        __syncthreads();
        for (int item = threadIdx.x; item < 384; item += 256) {
            int j = item / 96, c = item - j * 96;
            f32x4 A[4], Bm[4];
#pragma unroll
            for (int r = 0; r < 4; r++) {
                A[r]  = *(const f32x4*)&qs[c * LSTR + r * 16 + j * 4];
                Bm[r] = *(const f32x4*)&ks[c * LSTR + r * 16 + j * 4];
            }
            float rsB[4], csB[4], rsA[4], tot = 0.f;
#pragma unroll
            for (int r = 0; r < 4; r++) {
                rsB[r] = Bm[r][0] + Bm[r][1] + Bm[r][2] + Bm[r][3];
                rsA[r] = A[r][0] + A[r][1] + A[r][2] + A[r][3];
                tot += rsB[r];
            }
#pragma unroll
            for (int m = 0; m < 4; m++) csB[m] = Bm[0][m] + Bm[1][m] + Bm[2][m] + Bm[3][m];
#pragma unroll
            for (int r = 0; r < 4; r++) {
#pragma unroll
                for (int m = 0; m < 4; m++) {
                    float ab = A[r][0] * Bm[0][m] + A[r][1] * Bm[1][m]
                             + A[r][2] * Bm[2][m] + A[r][3] * Bm[3][m];
                    f1w[((size_t)((b * 128 + y0 + r) * 128 + x0 + cx * 16 + j * 4 + m)) * 96 + c]
                        = f2bf(8.f * ab + 2.f * rsA[r] * csB[m]);
                }
                f32x4 kt;
#pragma unroll
                for (int m = 0; m < 4; m++)
                    kt[m] = 64.f * Bm[r][m] + 16.f * (rsB[r] + csB[m]) + 4.f * tot;
                *(f32x4*)&ks[c * LSTR + r * 16 + j * 4] = kt;
            }
        }
        __syncthreads();
        float acc[6][6];
#pragma unroll
        for (int a = 0; a < 6; a++)
#pragma unroll
            for (int bb = 0; bb < 6; bb++) acc[a][bb] = 0.f;
        for (int l4 = 0; l4 < 16; l4++) {
            f32x4 qv4[6], kv4[6];
#pragma unroll
            for (int a = 0; a < 6; a++)
                qv4[a] = *(const f32x4*)&qs[(ty + 16 * a) * LSTR + l4 * 4];
#pragma unroll
            for (int bb = 0; bb < 6; bb++)
                kv4[bb] = *(const f32x4*)&ks[(tx + 16 * bb) * LSTR + l4 * 4];
#pragma unroll
            for (int a = 0; a < 6; a++)
#pragma unroll
                for (int bb = 0; bb < 6; bb++) {
                    acc[a][bb] += qv4[a][0] * kv4[bb][0];
                    acc[a][bb] += qv4[a][1] * kv4[bb][1];
                    acc[a][bb] += qv4[a][2] * kv4[bb][2];
                    acc[a][bb] += qv4[a][3] * kv4[bb][3];
                }
        }
#pragma unroll
        for (int a = 0; a < 6; a++)
#pragma unroll
            for (int bb = 0; bb < 6; bb++) accD[a][bb] += (double)acc[a][bb];
        __syncthreads();
    }
    int s128 = ys * 4 + xq;
#pragma unroll
    for (int a = 0; a < 6; a++)
#pragma unroll
        for (int bb = 0; bb < 6; bb++)
            part[((size_t)((b * 128 + s128) * 96 + ty + 16 * a)) * 96 + tx + 16 * bb]
                = (float)accD[a][bb];
}

// ---- GT[c][x][y] = f2bf(FQp - 0.5 FVN) transposed; planar vectorized reads ----
__global__ __launch_bounds__(256) void k_gprep2(
        const float* __restrict__ fqp, const u16* __restrict__ fvn,
        u16* __restrict__ gt) {
    __shared__ u16 lg[8 * 32 * 33];
    int blk = blockIdx.x;
    int b = blk / 192;
    int r = blk - b * 192;
    int yt = r / 48; r -= yt * 48;
    int xt = r / 12; int cc = r - xt * 12;
    int y0 = yt * 32, x0 = xt * 32, c0 = cc * 8;
    for (int idx = threadIdx.x; idx < 2048; idx += 256) {
        int cl = idx >> 8, rem = idx & 255, yy = rem >> 3, x4 = rem & 7;
        size_t off = ((size_t)((b * 96 + c0 + cl) * 128 + y0 + yy)) * 128 + x0 + x4 * 4;
        f32x4 q = *(const f32x4*)(fqp + off);
        const u16* vp = fvn + off;
        int la = (cl * 32 + yy) * 33 + x4 * 4;
#pragma unroll
        for (int u = 0; u < 4; u++)
            lg[la + u] = f2bf(q[u] - 0.5f * bf2f(vp[u]));
    }
    __syncthreads();
    for (int idx = threadIdx.x; idx < 8192; idx += 256) {
        int cl = idx >> 10, xl = (idx >> 5) & 31, yy = idx & 31;
        gt[((size_t)((b * 96 + c0 + cl) * 128 + x0 + xl)) * 128 + y0 + yy]
            = lg[(cl * 32 + yy) * 33 + xl];
    }
}

// ---- reduce 128 slices (f64) + temperature + row softmax -> bf16 weights ----
__global__ __launch_bounds__(128) void k_softmax(
        const float* __restrict__ part, const float* __restrict__ temp,
        u16* __restrict__ attnb) {
    __shared__ float red[128];
    int b = blockIdx.x / 96, i2 = blockIdx.x - b * 96;
    int j2 = threadIdx.x;
    float v = 0.f;
    if (j2 < 96) {
        double vd = 0.0;
        for (int s = 0; s < 128; s++)
            vd += (double)part[((size_t)((b * 128 + s) * 96 + i2)) * 96 + j2];
        v = (float)vd * temp[0];
    }
    red[j2] = (j2 < 96) ? v : -3.4e38f;
    __syncthreads();
    for (int off = 64; off >= 1; off >>= 1) {
        if (j2 < off) red[j2] = fmaxf(red[j2], red[j2 + off]);
        __syncthreads();
    }
    float mx = red[0];
    __syncthreads();
    float e = (j2 < 96) ? expf(v - mx) : 0.f;
    red[j2] = e;
    __syncthreads();
    for (int off = 64; off >= 1; off >>= 1) {
        if (j2 < off) red[j2] += red[j2 + off];
        __syncthreads();
    }
    float sum = red[0];
    if (j2 < 96) attnb[((size_t)(b * 96) + i2) * 96 + j2] = f2bf(e / sum);
}

// ---- FCFR[b][i][pix] = sum_j attn[i][j] * F1W[b][pix][j]  (bf16 MFMA) ----
__global__ __launch_bounds__(256) void k_fcfr2(
        const u16* __restrict__ attnb, const u16* __restrict__ f1w,
        u16* __restrict__ fc) {
    int b = blockIdx.x >> 6, pc = blockIdx.x & 63;
    int lane = threadIdx.x & 63, wv_ = threadIdx.x >> 6;
    int l15 = lane & 15, g = lane >> 4;
    int pbase = pc * 256 + wv_ * 64;
    f32x4 acc[6][4];
#pragma unroll
    for (int m = 0; m < 6; m++)
#pragma unroll
        for (int n = 0; n < 4; n++) acc[m][n] = (f32x4){0.f, 0.f, 0.f, 0.f};
#pragma unroll
    for (int ks = 0; ks < 3; ks++) {
        int k0 = ks * 32 + g * 8;
        i32x4 afr[6];
#pragma unroll
        for (int m = 0; m < 6; m++)
            afr[m] = *(const i32x4*)(attnb + ((size_t)(b * 96 + m * 16 + l15)) * 96 + k0);
#pragma unroll
        for (int n = 0; n < 4; n++) {
            i32x4 bfr = *(const i32x4*)(f1w + ((size_t)(b * 16384 + pbase + n * 16 + l15)) * 96 + k0);
#pragma unroll
            for (int m = 0; m < 6; m++)
                acc[m][n] = mfma16(afr[m], bfr, acc[m][n]);
        }
    }
#pragma unroll
    for (int m = 0; m < 6; m++)
#pragma unroll
        for (int n = 0; n < 4; n++)
#pragma unroll
            for (int r = 0; r < 4; r++) {
                int i2 = m * 16 + g * 4 + r;
                int pix = pbase + n * 16 + l15;
                fc[((size_t)(b * 96 + i2)) * HWSZ + pix] = f2bf(acc[m][n][r]);
            }
}

// ---- out = Fcfrout @ (F_Q - 0.5 F_V) + F_V  (bf16 MFMA, per (b,c) 128^3) ----
__global__ __launch_bounds__(256) void k_final(
        const u16* __restrict__ fc, const u16* __restrict__ gt,
        const u16* __restrict__ fvn, float* __restrict__ out) {
    int b = blockIdx.x / 96, c = blockIdx.x - b * 96;
    int lane = threadIdx.x & 63, wv_ = threadIdx.x >> 6;
    int l15 = lane & 15, g = lane >> 4;
    const u16* A = fc + ((size_t)(b * 96 + c)) * HWSZ;
    const u16* Bm = gt + ((size_t)(b * 96 + c)) * HWSZ;
    f32x4 acc[2][8];
#pragma unroll
    for (int mf = 0; mf < 2; mf++)
#pragma unroll
        for (int nf = 0; nf < 8; nf++) acc[mf][nf] = (f32x4){0.f, 0.f, 0.f, 0.f};
#pragma unroll
    for (int kc = 0; kc < 4; kc++) {
        int k0 = kc * 32 + g * 8;
        i32x4 af[2];
#pragma unroll
        for (int mf = 0; mf < 2; mf++)
            af[mf] = *(const i32x4*)(A + (size_t)(wv_ * 32 + mf * 16 + l15) * 128 + k0);
#pragma unroll
        for (int nf = 0; nf < 8; nf++) {
            i32x4 bf = *(const i32x4*)(Bm + (size_t)(nf * 16 + l15) * 128 + k0);
#pragma unroll
            for (int mf = 0; mf < 2; mf++)
                acc[mf][nf] = mfma16(af[mf], bf, acc[mf][nf]);
        }
    }
    const u16* V = fvn + ((size_t)(b * 96 + c)) * HWSZ;
    float* O = out + ((size_t)(b * 96 + c)) * HWSZ;
#pragma unroll
    for (int mf = 0; mf < 2; mf++)
#pragma unroll
        for (int nf = 0; nf < 8; nf++)
#pragma unroll
            for (int r = 0; r < 4; r++) {
                int y = wv_ * 32 + mf * 16 + g * 4 + r;
                int x = nf * 16 + l15;
                O[y * 128 + x] = acc[mf][nf][r] + bf2f(V[y * 128 + x]);
            }
}

extern "C" void kernel_launch(void* const* d_in, const int* in_sizes, int n_in,
                              void* d_out, int out_size, void* d_ws, size_t ws_size,
                              hipStream_t stream) {
    (void)in_sizes; (void)n_in;
    if (ws_size < (size_t)WS_NEED) {
        k_diag<<<2048, 256, 0, stream>>>((float*)d_out, out_size, (float)(ws_size >> 10));
        return;
    }
    const float* in1 = (const float*)d_in[0];
    const float* in2 = (const float*)d_in[1];
    const float* wq  = (const float*)d_in[2];
    const float* bq  = (const float*)d_in[3];
    const float* wk  = (const float*)d_in[4];
    const float* bk  = (const float*)d_in[5];
    const float* wv  = (const float*)d_in[6];
    const float* bv  = (const float*)d_in[7];
    const float* temp = (const float*)d_in[8];
    char* ws = (char*)d_ws;
    float* FQ   = (float*)(ws + OFF_FQ);     // planar
    float* FK   = (float*)(ws + OFF_FK);     // planar
    u16*  GT    = (u16*)(ws + OFF_GT);
    u16*  PAD1H = (u16*)(ws + OFF_PAD1H);
    u16*  PAD1L = (u16*)(ws + OFF_PAD1L);
    u16*  PAD2  = (u16*)(ws + OFF_PAD2);
    u16*  F1W   = (u16*)(ws + OFF_F1W);
    float* PART = (float*)(ws + OFF_PART);
    u16*  FCFR  = (u16*)(ws + OFF_FCFR);
    u16*  FVN   = (u16*)(ws + OFF_FVN);      // planar bf16 (old FVB slot)
    u16*  ATTNB = (u16*)(ws + OFF_ATTNB);
    u16*  WQK   = (u16*)(ws + OFF_WQK);
    u16*  WV    = (u16*)(ws + OFF_WV);

    k_trans2<<<2048, 256, 0, stream>>>(in1, in2, PAD1H, PAD1L, PAD2);
    k_weights_all<<<288, 128, 0, stream>>>(wq, wk, wv, WQK, WV);
    k_convqk6p<<<1024, 512, 0, stream>>>(PAD1H, PAD1L, WQK, bq, bk, FQ, FK);
    k_convv7p<<<1024, 512, 0, stream>>>(PAD2, WV, bv, FVN);
    k_pattn2p<<<1024, 256, 0, stream>>>(FQ, FK, F1W, PART);
    k_gprep2<<<1536, 256, 0, stream>>>(FQ, FVN, GT);     // GT over FK (dead after pattn)
    k_softmax<<<768, 128, 0, stream>>>(PART, temp, ATTNB);
    k_fcfr2<<<512, 256, 0, stream>>>(ATTNB, F1W, FCFR);  // FCFR over PAD2/PART (dead)
    k_final<<<768, 256, 0, stream>>>(FCFR, GT, FVN, (float*)d_out);
}